// Round 3
// baseline (7138.898 us; speedup 1.0000x reference)
//
#include <hip/hip_runtime.h>
#include <math.h>

// PhaseMultiHeadDecoder: B=4, S=1024, E=1024, H=16, hd=64, V=256
// Pipeline: rot tables -> embed(state) -> flash attn (D=128 real) -> complex FF GEMM
//           -> complex row norm -> readout GEMM (+biases)
#define B_ 4
#define S_ 1024
#define E_ 1024
#define H_ 16
#define DH_ 64
#define V_ 256

// ---------------- rotation cos/sin tables: tabs[3][2][1024] ----------------
__global__ void rot_kernel(const float* __restrict__ qr, const float* __restrict__ kr,
                           const float* __restrict__ vr, float* __restrict__ tabs) {
  int i = blockIdx.x * blockDim.x + threadIdx.x;
  if (i >= 3 * H_ * DH_) return;
  int which = i >> 10;          // H_*DH_ = 1024
  int j = i & 1023;
  const float* src = which == 0 ? qr : (which == 1 ? kr : vr);
  float s, c;
  sincosf(src[j], &s, &c);
  tabs[which * 2048 + j] = c;
  tabs[which * 2048 + 1024 + j] = s;
}

// ---------------- embed: state = tanh(te[x]) * exp(i*pos_phase) ----------------
__global__ void embed_kernel(const int* __restrict__ x, const float* __restrict__ te,
                             const float* __restrict__ pp,
                             float* __restrict__ sr, float* __restrict__ si) {
  int idx = blockIdx.x * 256 + threadIdx.x;   // < B*S*E = 4194304
  int e = idx & (E_ - 1);
  int bs = idx >> 10;                          // b*S + s
  int s = bs & (S_ - 1);
  int tok = x[bs];
  float m = tanhf(te[tok * E_ + e]);
  float sn, cs;
  sincosf(pp[s * E_ + e], &sn, &cs);
  sr[idx] = m * cs;
  si[idx] = m * sn;
}

// ---------------- flash attention, D = 128 = [real64 | imag64] ----------------
#define TQ 64
#define TK 16

__global__ __launch_bounds__(256, 2) void attn_kernel(
    const float* __restrict__ sr, const float* __restrict__ si,
    const float* __restrict__ tabs,
    float* __restrict__ aor, float* __restrict__ aoi) {
  __shared__ __align__(16) float Qs[TQ][132];
  __shared__ __align__(16) float Ks[TK][132];
  __shared__ __align__(16) float Vs[TK][132];

  const int qt = blockIdx.x, h = blockIdx.y, b = blockIdx.z;
  const int q0 = qt * TQ;
  const int tid = threadIdx.x;
  const float* qc  = tabs;
  const float* qs_ = tabs + 1024;
  const float* kc  = tabs + 2048;
  const float* ks_ = tabs + 3072;
  const float* vc  = tabs + 4096;
  const float* vs_ = tabs + 5120;

  // stage rotated Q tile: 64 rows x 128 (d<64: real, d>=64: imag)
  #pragma unroll
  for (int i = 0; i < 32; ++i) {
    int e2 = tid + i * 256;
    int row = e2 >> 7, d = e2 & 127, dd = d & 63;
    int g = (b * S_ + q0 + row) * E_ + h * 64 + dd;
    float re = sr[g], im = si[g];
    float c = qc[h * 64 + dd], s = qs_[h * 64 + dd];
    Qs[row][d] = (d < 64) ? (re * c - im * s) : (re * s + im * c);
  }

  const int r = tid >> 2, c4 = tid & 3;     // 4 threads per q-row
  const int lane = tid & 63;
  const int lanebase = lane & ~3;
  float o[32];
  #pragma unroll
  for (int t = 0; t < 32; ++t) o[t] = 0.f;
  float m = -1e30f, l = 0.f;

  const int nt = (q0 + TQ) / TK;
  for (int kt = 0; kt < nt; ++kt) {
    const int k0 = kt * TK;
    __syncthreads();
    // stage rotated K and V tiles
    #pragma unroll
    for (int i = 0; i < 8; ++i) {
      int e2 = tid + i * 256;               // 2048 = TK*128
      int row = e2 >> 7, d = e2 & 127, dd = d & 63;
      int g = (b * S_ + k0 + row) * E_ + h * 64 + dd;
      float re = sr[g], im = si[g];
      float ck = kc[h * 64 + dd], sk = ks_[h * 64 + dd];
      float cv = vc[h * 64 + dd], sv = vs_[h * 64 + dd];
      Ks[row][d] = (d < 64) ? (re * ck - im * sk) : (re * sk + im * ck);
      Vs[row][d] = (d < 64) ? (re * cv - im * sv) : (re * sv + im * cv);
    }
    __syncthreads();

    // scores: this thread handles kk = c4 + 4j, j<4
    float scv[4] = {0.f, 0.f, 0.f, 0.f};
    #pragma unroll
    for (int dd4 = 0; dd4 < 32; ++dd4) {
      float4 q4 = *(const float4*)&Qs[r][dd4 * 4];
      #pragma unroll
      for (int j = 0; j < 4; ++j) {
        float4 k4 = *(const float4*)&Ks[c4 + 4 * j][dd4 * 4];
        scv[j] += q4.x * k4.x + q4.y * k4.y + q4.z * k4.z + q4.w * k4.w;
      }
    }
    const int qg = q0 + r;
    #pragma unroll
    for (int j = 0; j < 4; ++j)
      if (k0 + c4 + 4 * j > qg) scv[j] = -1e30f;

    // online softmax across the 4 lanes of this row
    float mt = fmaxf(fmaxf(scv[0], scv[1]), fmaxf(scv[2], scv[3]));
    mt = fmaxf(mt, __shfl_xor(mt, 1, 64));
    mt = fmaxf(mt, __shfl_xor(mt, 2, 64));
    float mn = fmaxf(m, mt);
    float corr = __expf(m - mn);
    float p[4];
    float lsum = 0.f;
    #pragma unroll
    for (int j = 0; j < 4; ++j) { p[j] = __expf(scv[j] - mn); lsum += p[j]; }
    lsum += __shfl_xor(lsum, 1, 64);
    lsum += __shfl_xor(lsum, 2, 64);
    l = l * corr + lsum;
    m = mn;
    #pragma unroll
    for (int t = 0; t < 32; ++t) o[t] *= corr;

    // PV: p for key kk lives in lane (lanebase | kk&3) slot kk>>2
    #pragma unroll
    for (int kk = 0; kk < TK; ++kk) {
      float pv = __shfl(p[kk >> 2], lanebase | (kk & 3), 64);
      #pragma unroll
      for (int i = 0; i < 8; ++i) {
        float4 v4 = *(const float4*)&Vs[kk][(c4 + 4 * i) * 4];
        o[4 * i + 0] += pv * v4.x;
        o[4 * i + 1] += pv * v4.y;
        o[4 * i + 2] += pv * v4.z;
        o[4 * i + 3] += pv * v4.w;
      }
    }
  }
  float inv = 1.0f / l;
  int base = (b * S_ + q0 + r) * E_ + h * 64;
  #pragma unroll
  for (int i = 0; i < 8; ++i) {
    int d = (c4 + 4 * i) * 4;
    float4 w;
    w.x = o[4 * i + 0] * inv; w.y = o[4 * i + 1] * inv;
    w.z = o[4 * i + 2] * inv; w.w = o[4 * i + 3] * inv;
    if (d < 64) *(float4*)&aor[base + d] = w;
    else        *(float4*)&aoi[base + d - 64] = w;
  }
}

// ---------------- complex FF GEMM: (state+attn) @ (fr + i*fi) ----------------
#define FBM 128
#define FBN 64
#define FKT 16

__global__ __launch_bounds__(256, 2) void ff_kernel(
    const float* __restrict__ sr, const float* __restrict__ si,
    const float* __restrict__ aor, const float* __restrict__ aoi,
    const float* __restrict__ fr, const float* __restrict__ fi,
    float* __restrict__ t2r, float* __restrict__ t2i) {
  __shared__ __align__(16) float Art[FKT][FBM + 4];   // A transposed [kk][m]
  __shared__ __align__(16) float Ait[FKT][FBM + 4];
  __shared__ __align__(16) float Brs[FKT][FBN];
  __shared__ __align__(16) float Bis[FKT][FBN];
  const int tid = threadIdx.x;
  const int m0 = blockIdx.x * FBM, n0 = blockIdx.y * FBN;
  const int tr = tid >> 4, tc = tid & 15;

  float or_[8][4] = {};
  float oi_[8][4] = {};

  for (int kt = 0; kt < E_ / FKT; ++kt) {
    const int k0 = kt * FKT;
    __syncthreads();
    #pragma unroll
    for (int i = 0; i < 8; ++i) {
      int e2 = tid + i * 256;        // 2048 = 128*16
      int kk = e2 & 15, mm = e2 >> 4;
      int g = (m0 + mm) * E_ + k0 + kk;
      Art[kk][mm] = sr[g] + aor[g];
      Ait[kk][mm] = si[g] + aoi[g];
    }
    #pragma unroll
    for (int i = 0; i < 4; ++i) {
      int e2 = tid + i * 256;        // 1024 = 16*64
      int nn = e2 & 63, kk = e2 >> 6;
      int g = (k0 + kk) * E_ + n0 + nn;
      Brs[kk][nn] = fr[g];
      Bis[kk][nn] = fi[g];
    }
    __syncthreads();
    #pragma unroll
    for (int kk = 0; kk < FKT; ++kk) {
      float ar[8], ai[8], br[4], bi[4];
      *(float4*)&ar[0] = *(const float4*)&Art[kk][tr * 8];
      *(float4*)&ar[4] = *(const float4*)&Art[kk][tr * 8 + 4];
      *(float4*)&ai[0] = *(const float4*)&Ait[kk][tr * 8];
      *(float4*)&ai[4] = *(const float4*)&Ait[kk][tr * 8 + 4];
      *(float4*)&br[0] = *(const float4*)&Brs[kk][tc * 4];
      *(float4*)&bi[0] = *(const float4*)&Bis[kk][tc * 4];
      #pragma unroll
      for (int i = 0; i < 8; ++i) {
        #pragma unroll
        for (int j = 0; j < 4; ++j) {
          or_[i][j] += ar[i] * br[j] - ai[i] * bi[j];
          oi_[i][j] += ar[i] * bi[j] + ai[i] * br[j];
        }
      }
    }
  }
  #pragma unroll
  for (int i = 0; i < 8; ++i) {
    int row = (m0 + tr * 8 + i) * E_ + n0 + tc * 4;
    *(float4*)&t2r[row] = make_float4(or_[i][0], or_[i][1], or_[i][2], or_[i][3]);
    *(float4*)&t2i[row] = make_float4(oi_[i][0], oi_[i][1], oi_[i][2], oi_[i][3]);
  }
}

// ---------------- complex_norm, in place, one block per row ----------------
__global__ __launch_bounds__(256) void norm_kernel(float* __restrict__ t2r,
                                                   float* __restrict__ t2i) {
  const int row = blockIdx.x, tid = threadIdx.x;
  const int base = row * E_ + tid * 4;
  float4 zr = *(const float4*)&t2r[base];
  float4 zi = *(const float4*)&t2i[base];
  float mg[4];
  mg[0] = sqrtf(zr.x * zr.x + zi.x * zi.x);
  mg[1] = sqrtf(zr.y * zr.y + zi.y * zi.y);
  mg[2] = sqrtf(zr.z * zr.z + zi.z * zi.z);
  mg[3] = sqrtf(zr.w * zr.w + zi.w * zi.w);
  float s1 = mg[0] + mg[1] + mg[2] + mg[3];
  float s2 = mg[0]*mg[0] + mg[1]*mg[1] + mg[2]*mg[2] + mg[3]*mg[3];
  #pragma unroll
  for (int off = 1; off < 64; off <<= 1) {
    s1 += __shfl_xor(s1, off, 64);
    s2 += __shfl_xor(s2, off, 64);
  }
  __shared__ float ws1[4], ws2[4];
  if ((tid & 63) == 0) { ws1[tid >> 6] = s1; ws2[tid >> 6] = s2; }
  __syncthreads();
  s1 = ws1[0] + ws1[1] + ws1[2] + ws1[3];
  s2 = ws2[0] + ws2[1] + ws2[2] + ws2[3];
  float mean = s1 * (1.0f / 1024.0f);
  float var = (s2 - 1024.0f * mean * mean) * (1.0f / 1023.0f);  // ddof=1
  var = fmaxf(var, 0.0f);
  float inv_sd = 1.0f / (sqrtf(var) + 1e-5f);
  float sc[4];
  #pragma unroll
  for (int t = 0; t < 4; ++t)
    sc[t] = tanhf((mg[t] - mean) * inv_sd) / (mg[t] + 1e-5f);
  zr.x *= sc[0]; zr.y *= sc[1]; zr.z *= sc[2]; zr.w *= sc[3];
  zi.x *= sc[0]; zi.y *= sc[1]; zi.z *= sc[2]; zi.w *= sc[3];
  *(float4*)&t2r[base] = zr;
  *(float4*)&t2i[base] = zi;
}

// ---------------- readout: out = zr@wr^T + zi@wi^T + rb + ib ----------------
__global__ __launch_bounds__(256, 4) void ro_kernel(
    const float* __restrict__ zr, const float* __restrict__ zi,
    const float* __restrict__ wr, const float* __restrict__ wi,
    const float* __restrict__ rb, const float* __restrict__ ib,
    float* __restrict__ out) {
  __shared__ __align__(16) float Zrt[16][68];
  __shared__ __align__(16) float Zit[16][68];
  __shared__ __align__(16) float Wrt[16][68];
  __shared__ __align__(16) float Wit[16][68];
  const int tid = threadIdx.x;
  const int m0 = blockIdx.x * 64, v0 = blockIdx.y * 64;
  const int tr = tid >> 4, tc = tid & 15;
  float acc[4][4] = {};
  for (int kt = 0; kt < E_ / 16; ++kt) {
    const int k0 = kt * 16;
    __syncthreads();
    #pragma unroll
    for (int i = 0; i < 4; ++i) {
      int e2 = tid + i * 256;   // 1024 = 64*16
      int kk = e2 & 15, mm = e2 >> 4;
      Zrt[kk][mm] = zr[(m0 + mm) * E_ + k0 + kk];
      Zit[kk][mm] = zi[(m0 + mm) * E_ + k0 + kk];
      Wrt[kk][mm] = wr[(v0 + mm) * E_ + k0 + kk];
      Wit[kk][mm] = wi[(v0 + mm) * E_ + k0 + kk];
    }
    __syncthreads();
    #pragma unroll
    for (int kk = 0; kk < 16; ++kk) {
      float a[4], c2[4], b[4], d2[4];
      *(float4*)a  = *(const float4*)&Zrt[kk][tr * 4];
      *(float4*)c2 = *(const float4*)&Zit[kk][tr * 4];
      *(float4*)b  = *(const float4*)&Wrt[kk][tc * 4];
      *(float4*)d2 = *(const float4*)&Wit[kk][tc * 4];
      #pragma unroll
      for (int i = 0; i < 4; ++i) {
        #pragma unroll
        for (int j = 0; j < 4; ++j)
          acc[i][j] += a[i] * b[j] + c2[i] * d2[j];
      }
    }
  }
  float4 bias;
  bias.x = rb[v0 + tc * 4 + 0] + ib[v0 + tc * 4 + 0];
  bias.y = rb[v0 + tc * 4 + 1] + ib[v0 + tc * 4 + 1];
  bias.z = rb[v0 + tc * 4 + 2] + ib[v0 + tc * 4 + 2];
  bias.w = rb[v0 + tc * 4 + 3] + ib[v0 + tc * 4 + 3];
  #pragma unroll
  for (int i = 0; i < 4; ++i) {
    int mrow = (m0 + tr * 4 + i) * V_ + v0 + tc * 4;
    float4 o4;
    o4.x = acc[i][0] + bias.x;
    o4.y = acc[i][1] + bias.y;
    o4.z = acc[i][2] + bias.z;
    o4.w = acc[i][3] + bias.w;
    *(float4*)&out[mrow] = o4;
  }
}

extern "C" void kernel_launch(void* const* d_in, const int* in_sizes, int n_in,
                              void* d_out, int out_size, void* d_ws, size_t ws_size,
                              hipStream_t stream) {
  const int*   x    = (const int*)d_in[0];
  const float* te   = (const float*)d_in[1];
  const float* pp   = (const float*)d_in[2];
  const float* qr   = (const float*)d_in[3];
  const float* kr   = (const float*)d_in[4];
  const float* vr   = (const float*)d_in[5];
  const float* ffr  = (const float*)d_in[6];
  const float* ffi  = (const float*)d_in[7];
  const float* rorw = (const float*)d_in[8];
  const float* rorb = (const float*)d_in[9];
  const float* roiw = (const float*)d_in[10];
  const float* roib = (const float*)d_in[11];
  float* out = (float*)d_out;

  const size_t NBSE = (size_t)B_ * S_ * E_;   // 4194304
  float* sr   = (float*)d_ws;
  float* si   = sr + NBSE;
  float* aor  = si + NBSE;
  float* aoi  = aor + NBSE;
  float* t2r  = aoi + NBSE;
  float* t2i  = t2r + NBSE;
  float* tabs = t2i + NBSE;                   // 6144 floats

  rot_kernel<<<12, 256, 0, stream>>>(qr, kr, vr, tabs);
  embed_kernel<<<(int)(NBSE / 256), 256, 0, stream>>>(x, te, pp, sr, si);
  attn_kernel<<<dim3(S_ / TQ, H_, B_), 256, 0, stream>>>(sr, si, tabs, aor, aoi);
  ff_kernel<<<dim3((B_ * S_) / FBM, E_ / FBN), 256, 0, stream>>>(sr, si, aor, aoi,
                                                                 ffr, ffi, t2r, t2i);
  norm_kernel<<<B_ * S_, 256, 0, stream>>>(t2r, t2i);
  ro_kernel<<<dim3((B_ * S_) / 64, V_ / 64), 256, 0, stream>>>(t2r, t2i, rorw, roiw,
                                                               rorb, roib, out);
}

// Round 4
// 1382.415 us; speedup vs baseline: 5.1641x; 5.1641x over previous
//
#include <hip/hip_runtime.h>
#include <math.h>

// PhaseMultiHeadDecoder: B=4, S=1024, E=1024, H=16, hd=64, V=256
// rot/embed/attn: unchanged fp32. FF + readout: bf16 MFMA with hi/lo split
// (3-term: AhBh + AlBh + AhBl -> fp32-class accuracy), m97-style 128x128 tile.
#define B_ 4
#define S_ 1024
#define E_ 1024
#define H_ 16
#define V_ 256

typedef short s8bf __attribute__((ext_vector_type(8)));   // 8 bf16 (4 VGPR)
typedef float f4x __attribute__((ext_vector_type(4)));    // MFMA acc

__device__ __forceinline__ unsigned short bf16rne(float v) {
  unsigned u = __float_as_uint(v);
  return (unsigned short)((u + 0x7FFF + ((u >> 16) & 1)) >> 16);
}
__device__ __forceinline__ float bf2f(unsigned short h) {
  return __uint_as_float(((unsigned)h) << 16);
}
__device__ __forceinline__ void gload16(const void* g, void* l) {
  __builtin_amdgcn_global_load_lds((const __attribute__((address_space(1))) void*)g,
                                   (__attribute__((address_space(3))) void*)l, 16, 0, 0);
}

// ---------------- rotation cos/sin tables: tabs[3][2][1024] ----------------
__global__ void rot_kernel(const float* __restrict__ qr, const float* __restrict__ kr,
                           const float* __restrict__ vr, float* __restrict__ tabs) {
  int i = blockIdx.x * blockDim.x + threadIdx.x;
  if (i >= 3 * 1024) return;
  int which = i >> 10;
  int j = i & 1023;
  const float* src = which == 0 ? qr : (which == 1 ? kr : vr);
  float s, c;
  sincosf(src[j], &s, &c);
  tabs[which * 2048 + j] = c;
  tabs[which * 2048 + 1024 + j] = s;
}

// ---------------- embed: state = tanh(te[x]) * exp(i*pos_phase) ----------------
__global__ void embed_kernel(const int* __restrict__ x, const float* __restrict__ te,
                             const float* __restrict__ pp,
                             float* __restrict__ sr, float* __restrict__ si) {
  int idx = blockIdx.x * 256 + threadIdx.x;
  int e = idx & (E_ - 1);
  int bs = idx >> 10;
  int s = bs & (S_ - 1);
  int tok = x[bs];
  float m = tanhf(te[tok * E_ + e]);
  float sn, cs;
  sincosf(pp[s * E_ + e], &sn, &cs);
  sr[idx] = m * cs;
  si[idx] = m * sn;
}

// ---------------- flash attention, D = 128 = [real64 | imag64] (unchanged) ----------------
#define TQ 64
#define TK 16

__global__ __launch_bounds__(256, 2) void attn_kernel(
    const float* __restrict__ sr, const float* __restrict__ si,
    const float* __restrict__ tabs,
    float* __restrict__ aor, float* __restrict__ aoi) {
  __shared__ __align__(16) float Qs[TQ][132];
  __shared__ __align__(16) float Ks[TK][132];
  __shared__ __align__(16) float Vs[TK][132];

  const int qt = blockIdx.x, h = blockIdx.y, b = blockIdx.z;
  const int q0 = qt * TQ;
  const int tid = threadIdx.x;
  const float* qc  = tabs;
  const float* qs_ = tabs + 1024;
  const float* kc  = tabs + 2048;
  const float* ks_ = tabs + 3072;
  const float* vc  = tabs + 4096;
  const float* vs_ = tabs + 5120;

  #pragma unroll
  for (int i = 0; i < 32; ++i) {
    int e2 = tid + i * 256;
    int row = e2 >> 7, d = e2 & 127, dd = d & 63;
    int g = (b * S_ + q0 + row) * E_ + h * 64 + dd;
    float re = sr[g], im = si[g];
    float c = qc[h * 64 + dd], s = qs_[h * 64 + dd];
    Qs[row][d] = (d < 64) ? (re * c - im * s) : (re * s + im * c);
  }

  const int r = tid >> 2, c4 = tid & 3;
  const int lane = tid & 63;
  const int lanebase = lane & ~3;
  float o[32];
  #pragma unroll
  for (int t = 0; t < 32; ++t) o[t] = 0.f;
  float m = -1e30f, l = 0.f;

  const int nt = (q0 + TQ) / TK;
  for (int kt = 0; kt < nt; ++kt) {
    const int k0 = kt * TK;
    __syncthreads();
    #pragma unroll
    for (int i = 0; i < 8; ++i) {
      int e2 = tid + i * 256;
      int row = e2 >> 7, d = e2 & 127, dd = d & 63;
      int g = (b * S_ + k0 + row) * E_ + h * 64 + dd;
      float re = sr[g], im = si[g];
      float ck = kc[h * 64 + dd], sk = ks_[h * 64 + dd];
      float cv = vc[h * 64 + dd], sv = vs_[h * 64 + dd];
      Ks[row][d] = (d < 64) ? (re * ck - im * sk) : (re * sk + im * ck);
      Vs[row][d] = (d < 64) ? (re * cv - im * sv) : (re * sv + im * cv);
    }
    __syncthreads();

    float scv[4] = {0.f, 0.f, 0.f, 0.f};
    #pragma unroll
    for (int dd4 = 0; dd4 < 32; ++dd4) {
      float4 q4 = *(const float4*)&Qs[r][dd4 * 4];
      #pragma unroll
      for (int j = 0; j < 4; ++j) {
        float4 k4 = *(const float4*)&Ks[c4 + 4 * j][dd4 * 4];
        scv[j] += q4.x * k4.x + q4.y * k4.y + q4.z * k4.z + q4.w * k4.w;
      }
    }
    const int qg = q0 + r;
    #pragma unroll
    for (int j = 0; j < 4; ++j)
      if (k0 + c4 + 4 * j > qg) scv[j] = -1e30f;

    float mt = fmaxf(fmaxf(scv[0], scv[1]), fmaxf(scv[2], scv[3]));
    mt = fmaxf(mt, __shfl_xor(mt, 1, 64));
    mt = fmaxf(mt, __shfl_xor(mt, 2, 64));
    float mn = fmaxf(m, mt);
    float corr = __expf(m - mn);
    float p[4];
    float lsum = 0.f;
    #pragma unroll
    for (int j = 0; j < 4; ++j) { p[j] = __expf(scv[j] - mn); lsum += p[j]; }
    lsum += __shfl_xor(lsum, 1, 64);
    lsum += __shfl_xor(lsum, 2, 64);
    l = l * corr + lsum;
    m = mn;
    #pragma unroll
    for (int t = 0; t < 32; ++t) o[t] *= corr;

    #pragma unroll
    for (int kk = 0; kk < TK; ++kk) {
      float pv = __shfl(p[kk >> 2], lanebase | (kk & 3), 64);
      #pragma unroll
      for (int i = 0; i < 8; ++i) {
        float4 v4 = *(const float4*)&Vs[kk][(c4 + 4 * i) * 4];
        o[4 * i + 0] += pv * v4.x;
        o[4 * i + 1] += pv * v4.y;
        o[4 * i + 2] += pv * v4.z;
        o[4 * i + 3] += pv * v4.w;
      }
    }
  }
  float inv = 1.0f / l;
  int base = (b * S_ + q0 + r) * E_ + h * 64;
  #pragma unroll
  for (int i = 0; i < 8; ++i) {
    int d = (c4 + 4 * i) * 4;
    float4 w;
    w.x = o[4 * i + 0] * inv; w.y = o[4 * i + 1] * inv;
    w.z = o[4 * i + 2] * inv; w.w = o[4 * i + 3] * inv;
    if (d < 64) *(float4*)&aor[base + d] = w;
    else        *(float4*)&aoi[base + d - 64] = w;
  }
}

// ---------------- split A = state+attn -> Ahl[4096][hi2048|lo2048] bf16 ----------------
__global__ void split_a_kernel(const float* __restrict__ sr, const float* __restrict__ si,
                               const float* __restrict__ aor, const float* __restrict__ aoi,
                               unsigned short* __restrict__ Ahl) {
  int idx = blockIdx.x * 256 + threadIdx.x;        // 4096*512
  int m = idx >> 9;
  int j4 = (idx & 511) * 4;
  float4 v;
  if (j4 < 1024) {
    float4 a = *(const float4*)&sr[(size_t)m * 1024 + j4];
    float4 b = *(const float4*)&aor[(size_t)m * 1024 + j4];
    v = make_float4(a.x + b.x, a.y + b.y, a.z + b.z, a.w + b.w);
  } else {
    float4 a = *(const float4*)&si[(size_t)m * 1024 + j4 - 1024];
    float4 b = *(const float4*)&aoi[(size_t)m * 1024 + j4 - 1024];
    v = make_float4(a.x + b.x, a.y + b.y, a.z + b.z, a.w + b.w);
  }
  ushort4 h, l;
  h.x = bf16rne(v.x); l.x = bf16rne(v.x - bf2f(h.x));
  h.y = bf16rne(v.y); l.y = bf16rne(v.y - bf2f(h.y));
  h.z = bf16rne(v.z); l.z = bf16rne(v.z - bf2f(h.z));
  h.w = bf16rne(v.w); l.w = bf16rne(v.w - bf2f(h.w));
  *(ushort4*)&Ahl[(size_t)m * 4096 + j4] = h;
  *(ushort4*)&Ahl[(size_t)m * 4096 + 2048 + j4] = l;
}

// ---------------- split+transpose FF weight: Bt[n=2048][hi2048|lo2048] ----------------
// Bv[k][n] (2048x2048) = [[fr; -fi] | [fi; fr]];  Bt[n][k]=split(Bv[k][n])
__global__ void split_b_kernel(const float* __restrict__ fr, const float* __restrict__ fi,
                               unsigned short* __restrict__ Bt) {
  __shared__ float tile[32][33];
  const int k0 = blockIdx.x * 32, n0 = blockIdx.y * 32;
  const int tid = threadIdx.x;
  #pragma unroll
  for (int p = 0; p < 4; ++p) {
    int e = p * 256 + tid;
    int kk = e >> 5, nn = e & 31;
    int k = k0 + kk, n = n0 + nn;
    float v;
    if (n < 1024) v = (k < 1024) ? fr[(size_t)k * 1024 + n] : -fi[(size_t)(k - 1024) * 1024 + n];
    else          v = (k < 1024) ? fi[(size_t)k * 1024 + (n - 1024)]
                                 : fr[(size_t)(k - 1024) * 1024 + (n - 1024)];
    tile[kk][nn] = v;
  }
  __syncthreads();
  #pragma unroll
  for (int p = 0; p < 4; ++p) {
    int e = p * 256 + tid;
    int nn = e >> 5, kk = e & 31;
    float v = tile[kk][nn];
    unsigned short h = bf16rne(v);
    unsigned short l = bf16rne(v - bf2f(h));
    Bt[(size_t)(n0 + nn) * 4096 + (k0 + kk)] = h;
    Bt[(size_t)(n0 + nn) * 4096 + 2048 + (k0 + kk)] = l;
  }
}

// ---------------- split readout weight: Wt[v=256][hi2048|lo2048], Wc=[wr|wi] ----------------
__global__ void split_w_kernel(const float* __restrict__ wr, const float* __restrict__ wi,
                               unsigned short* __restrict__ Wt) {
  int idx = blockIdx.x * 256 + threadIdx.x;        // 256*512
  int v = idx >> 9;
  int k4 = (idx & 511) * 4;
  float4 a = (k4 < 1024) ? *(const float4*)&wr[(size_t)v * 1024 + k4]
                         : *(const float4*)&wi[(size_t)v * 1024 + k4 - 1024];
  ushort4 h, l;
  h.x = bf16rne(a.x); l.x = bf16rne(a.x - bf2f(h.x));
  h.y = bf16rne(a.y); l.y = bf16rne(a.y - bf2f(h.y));
  h.z = bf16rne(a.z); l.z = bf16rne(a.z - bf2f(h.z));
  h.w = bf16rne(a.w); l.w = bf16rne(a.w - bf2f(h.w));
  *(ushort4*)&Wt[(size_t)v * 4096 + k4] = h;
  *(ushort4*)&Wt[(size_t)v * 4096 + 2048 + k4] = l;
}

// ---------------- split-bf16 MFMA GEMM, m97 structure: 128x128 tile, BK=64 ----------------
// Logical K=6144 = [Ah|Al|Ah] x [Bh;Bh;Bl].  A phys col = k&4095; B phys col:
// k<4096 -> k&2047 (hi), else k-2048 (lo).  FF: N=2048 ([t2r|t2i]); RO: N=256 (+bias).
template<bool RO>
__global__ __launch_bounds__(256, 2) void gemm_split(
    const unsigned short* __restrict__ A,   // [4096][4096] bf16 bits
    const unsigned short* __restrict__ Bt,  // [N][4096] bf16 bits
    float* __restrict__ o0, float* __restrict__ o1,
    const float* __restrict__ br, const float* __restrict__ bi) {
  __shared__ short As[128 * 64];
  __shared__ short Bs[128 * 64];
  const int tid = threadIdx.x;
  const int lane = tid & 63, wid = tid >> 6;
  const int m0 = blockIdx.x * 128, n0 = blockIdx.y * 128;
  const int wr = wid >> 1, wc = wid & 1;
  const int cl = lane & 15, rg = lane >> 4;

  f4x acc[4][4] = {};
  const int cbase = wid * 256;   // this wave's 256 16B-chunks of each 16KB tile

  for (int kt = 0; kt < 96; ++kt) {
    const int k0 = kt * 64;
    const int pa = k0 & 4095;
    const int pb = (k0 < 4096) ? (k0 & 2047) : (k0 - 2048);
    #pragma unroll
    for (int it = 0; it < 4; ++it) {
      int c = cbase + it * 64 + lane;
      gload16(A + (size_t)(m0 + (c >> 3)) * 4096 + pa + (c & 7) * 8,
              As + (cbase + it * 64) * 8);
      gload16(Bt + (size_t)(n0 + (c >> 3)) * 4096 + pb + (c & 7) * 8,
              Bs + (cbase + it * 64) * 8);
    }
    __syncthreads();   // drains vmcnt -> LDS tiles ready
    #pragma unroll
    for (int ks = 0; ks < 2; ++ks) {
      s8bf a[4], b[4];
      #pragma unroll
      for (int ms = 0; ms < 4; ++ms)
        a[ms] = *(const s8bf*)&As[(wr * 64 + ms * 16 + cl) * 64 + ks * 32 + rg * 8];
      #pragma unroll
      for (int ns = 0; ns < 4; ++ns)
        b[ns] = *(const s8bf*)&Bs[(wc * 64 + ns * 16 + cl) * 64 + ks * 32 + rg * 8];
      #pragma unroll
      for (int ms = 0; ms < 4; ++ms)
        #pragma unroll
        for (int ns = 0; ns < 4; ++ns)
          acc[ms][ns] = __builtin_amdgcn_mfma_f32_16x16x32_bf16(a[ms], b[ns], acc[ms][ns], 0, 0, 0);
    }
    __syncthreads();   // protect LDS before next stage
  }

  const int colbase = n0 + wc * 64;
  if (!RO) {
    float* dst = (colbase < 1024) ? o0 : o1;
    const int cb = colbase & 1023;
    #pragma unroll
    for (int ms = 0; ms < 4; ++ms)
      #pragma unroll
      for (int r2 = 0; r2 < 4; ++r2) {
        const int grow = m0 + wr * 64 + ms * 16 + rg * 4 + r2;
        #pragma unroll
        for (int ns = 0; ns < 4; ++ns)
          dst[(size_t)grow * 1024 + cb + ns * 16 + cl] = acc[ms][ns][r2];
      }
  } else {
    #pragma unroll
    for (int ms = 0; ms < 4; ++ms)
      #pragma unroll
      for (int r2 = 0; r2 < 4; ++r2) {
        const int grow = m0 + wr * 64 + ms * 16 + rg * 4 + r2;
        #pragma unroll
        for (int ns = 0; ns < 4; ++ns) {
          const int gcol = colbase + ns * 16 + cl;
          o0[(size_t)grow * 256 + gcol] = acc[ms][ns][r2] + br[gcol] + bi[gcol];
        }
      }
  }
}

// ---------------- complex_norm fused with Z split: Zhl[4096][hi2048|lo2048] ----------------
__global__ __launch_bounds__(256) void norm_split_kernel(
    const float* __restrict__ t2r, const float* __restrict__ t2i,
    unsigned short* __restrict__ Z) {
  const int row = blockIdx.x, tid = threadIdx.x;
  const int base = row * E_ + tid * 4;
  float4 zr = *(const float4*)&t2r[base];
  float4 zi = *(const float4*)&t2i[base];
  float mg[4];
  mg[0] = sqrtf(zr.x * zr.x + zi.x * zi.x);
  mg[1] = sqrtf(zr.y * zr.y + zi.y * zi.y);
  mg[2] = sqrtf(zr.z * zr.z + zi.z * zi.z);
  mg[3] = sqrtf(zr.w * zr.w + zi.w * zi.w);
  float s1 = mg[0] + mg[1] + mg[2] + mg[3];
  float s2 = mg[0]*mg[0] + mg[1]*mg[1] + mg[2]*mg[2] + mg[3]*mg[3];
  #pragma unroll
  for (int off = 1; off < 64; off <<= 1) {
    s1 += __shfl_xor(s1, off, 64);
    s2 += __shfl_xor(s2, off, 64);
  }
  __shared__ float ws1[4], ws2[4];
  if ((tid & 63) == 0) { ws1[tid >> 6] = s1; ws2[tid >> 6] = s2; }
  __syncthreads();
  s1 = ws1[0] + ws1[1] + ws1[2] + ws1[3];
  s2 = ws2[0] + ws2[1] + ws2[2] + ws2[3];
  float mean = s1 * (1.0f / 1024.0f);
  float var = (s2 - 1024.0f * mean * mean) * (1.0f / 1023.0f);  // ddof=1
  var = fmaxf(var, 0.0f);
  float inv_sd = 1.0f / (sqrtf(var) + 1e-5f);
  float sc[4];
  #pragma unroll
  for (int t = 0; t < 4; ++t)
    sc[t] = tanhf((mg[t] - mean) * inv_sd) / (mg[t] + 1e-5f);
  float a0 = zr.x * sc[0], a1 = zr.y * sc[1], a2 = zr.z * sc[2], a3 = zr.w * sc[3];
  float b0 = zi.x * sc[0], b1 = zi.y * sc[1], b2 = zi.z * sc[2], b3 = zi.w * sc[3];
  ushort4 hr, lr, hi_, li_;
  hr.x = bf16rne(a0); lr.x = bf16rne(a0 - bf2f(hr.x));
  hr.y = bf16rne(a1); lr.y = bf16rne(a1 - bf2f(hr.y));
  hr.z = bf16rne(a2); lr.z = bf16rne(a2 - bf2f(hr.z));
  hr.w = bf16rne(a3); lr.w = bf16rne(a3 - bf2f(hr.w));
  hi_.x = bf16rne(b0); li_.x = bf16rne(b0 - bf2f(hi_.x));
  hi_.y = bf16rne(b1); li_.y = bf16rne(b1 - bf2f(hi_.y));
  hi_.z = bf16rne(b2); li_.z = bf16rne(b2 - bf2f(hi_.z));
  hi_.w = bf16rne(b3); li_.w = bf16rne(b3 - bf2f(hi_.w));
  const size_t zb = (size_t)row * 4096 + tid * 4;
  *(ushort4*)&Z[zb]        = hr;   // zr hi
  *(ushort4*)&Z[zb + 1024] = hi_;  // zi hi
  *(ushort4*)&Z[zb + 2048] = lr;   // zr lo
  *(ushort4*)&Z[zb + 3072] = li_;  // zi lo
}

extern "C" void kernel_launch(void* const* d_in, const int* in_sizes, int n_in,
                              void* d_out, int out_size, void* d_ws, size_t ws_size,
                              hipStream_t stream) {
  const int*   x    = (const int*)d_in[0];
  const float* te   = (const float*)d_in[1];
  const float* pp   = (const float*)d_in[2];
  const float* qr   = (const float*)d_in[3];
  const float* kr   = (const float*)d_in[4];
  const float* vr   = (const float*)d_in[5];
  const float* ffr  = (const float*)d_in[6];
  const float* ffi  = (const float*)d_in[7];
  const float* rorw = (const float*)d_in[8];
  const float* rorb = (const float*)d_in[9];
  const float* roiw = (const float*)d_in[10];
  const float* roib = (const float*)d_in[11];
  float* out = (float*)d_out;

  const size_t NBSE = (size_t)B_ * S_ * E_;        // 4194304
  float* sr  = (float*)d_ws;                       // 16MB, reused as t2r
  float* si  = sr + NBSE;                          // 16MB, reused as t2i
  float* aor = si + NBSE;                          // 16MB ┐ reused as Zhl (32MB)
  float* aoi = aor + NBSE;                         // 16MB ┘
  unsigned short* Ahl = (unsigned short*)(aoi + NBSE);   // 32MB
  unsigned short* Bt  = Ahl + (size_t)4096 * 4096;       // 16MB
  unsigned short* Wt  = Bt + (size_t)2048 * 4096;        // 2MB
  float* tabs = (float*)(Wt + (size_t)256 * 4096);       // 24KB
  unsigned short* Zhl = (unsigned short*)aor;
  float* t2r = sr;
  float* t2i = si;

  rot_kernel<<<12, 256, 0, stream>>>(qr, kr, vr, tabs);
  embed_kernel<<<(int)(NBSE / 256), 256, 0, stream>>>(x, te, pp, sr, si);
  attn_kernel<<<dim3(S_ / TQ, H_, B_), 256, 0, stream>>>(sr, si, tabs, aor, aoi);
  split_b_kernel<<<dim3(64, 64), 256, 0, stream>>>(ffr, ffi, Bt);
  split_w_kernel<<<512, 256, 0, stream>>>(rorw, roiw, Wt);
  split_a_kernel<<<8192, 256, 0, stream>>>(sr, si, aor, aoi, Ahl);
  gemm_split<false><<<dim3(32, 16), 256, 0, stream>>>(Ahl, Bt, t2r, t2i, nullptr, nullptr);
  norm_split_kernel<<<B_ * S_, 256, 0, stream>>>(t2r, t2i, Zhl);
  gemm_split<true><<<dim3(32, 2), 256, 0, stream>>>(Zhl, Wt, out, nullptr, rorb, roib);
}

// Round 5
// 433.515 us; speedup vs baseline: 16.4675x; 3.1888x over previous
//
#include <hip/hip_runtime.h>
#include <math.h>

// PhaseMultiHeadDecoder: B=4, S=1024, E=1024, H=16, hd=64, V=256
// attn: bf16 MFMA flash (raw-state Q/V, delta-rotated split K, transposed scores)
// FF + readout: split-bf16 MFMA GEMM (3-term), m97-style 128x128 tile.
#define B_ 4
#define S_ 1024
#define E_ 1024
#define H_ 16
#define V_ 256

typedef short s8bf __attribute__((ext_vector_type(8)));   // 8 bf16 (4 VGPR)
typedef short s4bf __attribute__((ext_vector_type(4)));   // 4 bf16 (2 VGPR)
typedef float f4x __attribute__((ext_vector_type(4)));    // MFMA acc

__device__ __forceinline__ unsigned short bf16rne(float v) {
  unsigned u = __float_as_uint(v);
  return (unsigned short)((u + 0x7FFF + ((u >> 16) & 1)) >> 16);
}
__device__ __forceinline__ float bf2f(unsigned short h) {
  return __uint_as_float(((unsigned)h) << 16);
}
__device__ __forceinline__ void gload16(const void* g, void* l) {
  __builtin_amdgcn_global_load_lds((const __attribute__((address_space(1))) void*)g,
                                   (__attribute__((address_space(3))) void*)l, 16, 0, 0);
}

#if defined(__has_builtin)
#if __has_builtin(__builtin_amdgcn_mfma_f32_16x16x16bf16_1k)
#define MFMA16(a, b, c) __builtin_amdgcn_mfma_f32_16x16x16bf16_1k(a, b, c, 0, 0, 0)
#endif
#endif
#ifndef MFMA16
__device__ __forceinline__ f4x mfma16_asm(s4bf a, s4bf b, f4x c) {
  asm volatile("v_mfma_f32_16x16x16_bf16 %0, %1, %2, %0" : "+v"(c) : "v"(a), "v"(b));
  return c;
}
#define MFMA16(a, b, c) mfma16_asm(a, b, c)
#endif

// ---------------- rotation cos/sin tables: tabs[3][2][1024] ----------------
__global__ void rot_kernel(const float* __restrict__ qr, const float* __restrict__ kr,
                           const float* __restrict__ vr, float* __restrict__ tabs) {
  int i = blockIdx.x * blockDim.x + threadIdx.x;
  if (i >= 3 * 1024) return;
  int which = i >> 10;
  int j = i & 1023;
  const float* src = which == 0 ? qr : (which == 1 ? kr : vr);
  float s, c;
  sincosf(src[j], &s, &c);
  tabs[which * 2048 + j] = c;
  tabs[which * 2048 + 1024 + j] = s;
}

// ---------------- embed: state = tanh(te[x]) * exp(i*pos_phase) ----------------
__global__ void embed_kernel(const int* __restrict__ x, const float* __restrict__ te,
                             const float* __restrict__ pp,
                             float* __restrict__ sr, float* __restrict__ si) {
  int idx = blockIdx.x * 256 + threadIdx.x;
  int e = idx & (E_ - 1);
  int bs = idx >> 10;
  int s = bs & (S_ - 1);
  int tok = x[bs];
  float m = tanhf(te[tok * E_ + e]);
  float sn, cs;
  sincosf(pp[s * E_ + e], &sn, &cs);
  sr[idx] = m * cs;
  si[idx] = m * sn;
}

// ---------------- K'/V' prep: K rotated by (thq-thk), split hi/lo; V raw bf16 ----
// K' frag layout per 16-key tile (4096 shorts): ((f*4+kg)*16+key)*8+j,
//   feature c: f=c>>5, kg=(c>>3)&3, j=c&7; c = [k'r hi(0-63)|k'i hi|k'r lo|k'i lo]
// V' per tile (2048 shorts): ((mt*4+kgk)*16+d16)*4+jk; d=[re|im], key: kgk=key>>2,jk=key&3
__global__ __launch_bounds__(256) void qkv_prep_kernel(
    const float* __restrict__ sr, const float* __restrict__ si,
    const float* __restrict__ tabs,
    unsigned short* __restrict__ Kd, unsigned short* __restrict__ Vd) {
  __shared__ unsigned short Kl2[8192];
  __shared__ unsigned short Vl2[4096];
  const int kt2 = blockIdx.x;          // 32-key group, 0..31
  const int bh = blockIdx.y;           // 0..63
  const int b = bh >> 4, h = bh & 15;
  const int tid = threadIdx.x;
  const float* qc = tabs + h * 64;
  const float* qs = tabs + 1024 + h * 64;
  const float* kc = tabs + 2048 + h * 64;
  const float* ks = tabs + 3072 + h * 64;
  #pragma unroll
  for (int p = 0; p < 8; ++p) {
    int id = p * 256 + tid;            // 2048 items
    int sl = id >> 6;                  // local key 0..31
    int dd = id & 63;
    int s = kt2 * 32 + sl;
    size_t g = ((size_t)(b * 1024 + s)) * 1024 + h * 64 + dd;
    float re = sr[g], im = si[g];
    float cq = qc[dd], sq = qs[dd], ck = kc[dd], sk = ks[dd];
    float cd = cq * ck + sq * sk;      // cos(thq - thk)
    float sd = sq * ck - cq * sk;      // sin(thq - thk)
    float kr = re * cd + im * sd;      // k-state rotated by -delta
    float ki = im * cd - re * sd;
    unsigned short hr = bf16rne(kr), lr = bf16rne(kr - bf2f(hr));
    unsigned short hi2 = bf16rne(ki), li2 = bf16rne(ki - bf2f(hi2));
    int t = sl >> 4, key = sl & 15;
    int c0 = dd, c1 = 64 + dd, c2 = 128 + dd, c3 = 192 + dd;
    #define KOFF(c) (t * 4096 + ((((c) >> 5) * 4 + (((c) >> 3) & 3)) * 16 + key) * 8 + ((c) & 7))
    Kl2[KOFF(c0)] = hr;  Kl2[KOFF(c1)] = hi2;
    Kl2[KOFF(c2)] = lr;  Kl2[KOFF(c3)] = li2;
    #undef KOFF
    int kgk = key >> 2, jk = key & 3;
    #define VOFF(d) (t * 2048 + ((((d) >> 4) * 4 + kgk) * 16 + ((d) & 15)) * 4 + jk)
    Vl2[VOFF(dd)] = bf16rne(re);
    Vl2[VOFF(64 + dd)] = bf16rne(im);
    #undef VOFF
  }
  __syncthreads();
  unsigned short* kdst = Kd + ((size_t)(bh * 64 + kt2 * 2)) * 4096;
  unsigned short* vdst = Vd + ((size_t)(bh * 64 + kt2 * 2)) * 2048;
  #pragma unroll
  for (int p = 0; p < 4; ++p) {
    int c = p * 256 + tid;
    ((int4*)kdst)[c] = ((const int4*)Kl2)[c];
  }
  #pragma unroll
  for (int p = 0; p < 2; ++p) {
    int c = p * 256 + tid;
    ((int4*)vdst)[c] = ((const int4*)Vl2)[c];
  }
}

// ---------------- MFMA flash attention ----------------
// Block: 128 q-rows for one (b,h); 4 waves x 32 q (2 qn-tiles of 16).
// Scores^T = mfma_16x16x32(K' frags, Q^T frags) over logical K=384 (3-term split).
// P^T (C layout) == B-frag of 16x16x16 -> PV = mfma16(V'^T, P^T), no shuffles.
__global__ __launch_bounds__(256, 2) void attn_mfma_kernel(
    const float* __restrict__ sr, const float* __restrict__ si,
    const unsigned short* __restrict__ Kd, const unsigned short* __restrict__ Vd,
    const float* __restrict__ tabs,
    float* __restrict__ aor, float* __restrict__ aoi) {
  __shared__ __align__(16) unsigned short Klds[4096];
  __shared__ __align__(16) unsigned short Vlds[2048];
  const int qt = blockIdx.x;           // 0..7
  const int bh = blockIdx.y;           // 0..63
  const int b = bh >> 4, h = bh & 15;
  const int tid = threadIdx.x, lane = tid & 63, wid = tid >> 6;
  const int cl = lane & 15, kg = lane >> 4;
  const int q0 = qt * 128, qw0 = q0 + wid * 32;

  // Q^T b-frags from raw state, exact hi/lo split (in registers)
  s8bf qh[2][4], ql[2][4];
  #pragma unroll
  for (int qn = 0; qn < 2; ++qn) {
    int q = qw0 + qn * 16 + cl;
    const float* srow = sr + ((size_t)(b * 1024 + q)) * 1024 + h * 64;
    const float* irow = si + ((size_t)(b * 1024 + q)) * 1024 + h * 64;
    #pragma unroll
    for (int fa = 0; fa < 4; ++fa) {
      int f0 = fa * 32 + kg * 8;
      const float* src = (f0 < 64) ? (srow + f0) : (irow + (f0 - 64));
      float4 v0 = *(const float4*)src;
      float4 v1 = *(const float4*)(src + 4);
      float vv[8] = {v0.x, v0.y, v0.z, v0.w, v1.x, v1.y, v1.z, v1.w};
      #pragma unroll
      for (int j = 0; j < 8; ++j) {
        unsigned short hh = bf16rne(vv[j]);
        unsigned short lo = bf16rne(vv[j] - bf2f(hh));
        qh[qn][fa][j] = (short)hh;
        ql[qn][fa][j] = (short)lo;
      }
    }
  }

  f4x acc[2][8] = {};                   // out^T: [qn][mt], d = mt*16+kg*4+r
  float m_[2] = {-1e30f, -1e30f}, l_[2] = {0.f, 0.f};
  const int ktmax = qt * 8 + 8;
  const int wqmax = qw0 + 31;

  for (int kt = 0; kt < ktmax; ++kt) {
    __syncthreads();
    const unsigned short* kbase = Kd + ((size_t)(bh * 64 + kt)) * 4096;
    const unsigned short* vbase = Vd + ((size_t)(bh * 64 + kt)) * 2048;
    #pragma unroll
    for (int it = 0; it < 2; ++it) {
      int c = wid * 128 + it * 64 + lane;
      gload16(kbase + (size_t)c * 8, Klds + (wid * 128 + it * 64) * 8);
    }
    gload16(vbase + (size_t)(wid * 64 + lane) * 8, Vlds + (wid * 64) * 8);
    __syncthreads();
    const int k0 = kt * 16;
    if (k0 <= wqmax) {
      // scores^T over 12 k-steps: [QhKh x4 | QlKh x4 | QhKl x4]
      f4x sc[2] = {};
      #pragma unroll
      for (int ks = 0; ks < 12; ++ks) {
        int f = (ks < 4) ? ks : ks - 4;
        s8bf ka = *(const s8bf*)&Klds[f * 512 + lane * 8];
        s8bf qb0 = (ks < 4) ? qh[0][ks] : (ks < 8 ? ql[0][ks - 4] : qh[0][ks - 8]);
        s8bf qb1 = (ks < 4) ? qh[1][ks] : (ks < 8 ? ql[1][ks - 4] : qh[1][ks - 8]);
        sc[0] = __builtin_amdgcn_mfma_f32_16x16x32_bf16(ka, qb0, sc[0], 0, 0, 0);
        sc[1] = __builtin_amdgcn_mfma_f32_16x16x32_bf16(ka, qb1, sc[1], 0, 0, 0);
      }
      #pragma unroll
      for (int qn = 0; qn < 2; ++qn) {
        int qcol = qw0 + qn * 16 + cl;
        if (k0 + 15 > qw0 + qn * 16) {
          #pragma unroll
          for (int r = 0; r < 4; ++r)
            if (k0 + kg * 4 + r > qcol) sc[qn][r] = -1e30f;
        }
        // online softmax (keys live on kg*4+r -> in-lane + xor16 + xor32)
        float mx = fmaxf(fmaxf(sc[qn][0], sc[qn][1]), fmaxf(sc[qn][2], sc[qn][3]));
        mx = fmaxf(mx, __shfl_xor(mx, 16, 64));
        mx = fmaxf(mx, __shfl_xor(mx, 32, 64));
        float mn = fmaxf(m_[qn], mx);
        float corr = __expf(m_[qn] - mn);
        float p0 = __expf(sc[qn][0] - mn), p1 = __expf(sc[qn][1] - mn);
        float p2 = __expf(sc[qn][2] - mn), p3 = __expf(sc[qn][3] - mn);
        float s0 = p0 + p1 + p2 + p3;
        s0 += __shfl_xor(s0, 16, 64);
        s0 += __shfl_xor(s0, 32, 64);
        l_[qn] = l_[qn] * corr + s0;
        bool resc = mn > m_[qn];
        m_[qn] = mn;
        if (__any(resc)) {
          #pragma unroll
          for (int mt = 0; mt < 8; ++mt) acc[qn][mt] *= corr;
        }
        s4bf pb;
        pb[0] = (short)bf16rne(p0); pb[1] = (short)bf16rne(p1);
        pb[2] = (short)bf16rne(p2); pb[3] = (short)bf16rne(p3);
        #pragma unroll
        for (int mt = 0; mt < 8; ++mt) {
          s4bf va = *(const s4bf*)&Vlds[mt * 256 + lane * 4];
          acc[qn][mt] = MFMA16(va, pb, acc[qn][mt]);
        }
      }
    }
  }
  // epilogue: /l, rotate by exp(i*thv), store float4 per (mt,kg)
  #pragma unroll
  for (int qn = 0; qn < 2; ++qn) {
    float linv = 1.0f / l_[qn];
    int q = qw0 + qn * 16 + cl;
    size_t obase = ((size_t)(b * 1024 + q)) * 1024 + h * 64;
    #pragma unroll
    for (int mt = 0; mt < 4; ++mt) {
      float vr_[4], vi_[4];
      #pragma unroll
      for (int r = 0; r < 4; ++r) {
        int d0 = mt * 16 + kg * 4 + r;
        float orv = acc[qn][mt][r] * linv;
        float oiv = acc[qn][mt + 4][r] * linv;
        float c = tabs[4096 + h * 64 + d0], s = tabs[5120 + h * 64 + d0];
        vr_[r] = orv * c - oiv * s;
        vi_[r] = orv * s + oiv * c;
      }
      *(float4*)&aor[obase + mt * 16 + kg * 4] = *(float4*)vr_;
      *(float4*)&aoi[obase + mt * 16 + kg * 4] = *(float4*)vi_;
    }
  }
}

// ---------------- split A = state+attn -> Ahl[4096][hi2048|lo2048] bf16 ----------------
__global__ void split_a_kernel(const float* __restrict__ sr, const float* __restrict__ si,
                               const float* __restrict__ aor, const float* __restrict__ aoi,
                               unsigned short* __restrict__ Ahl) {
  int idx = blockIdx.x * 256 + threadIdx.x;        // 4096*512
  int m = idx >> 9;
  int j4 = (idx & 511) * 4;
  float4 v;
  if (j4 < 1024) {
    float4 a = *(const float4*)&sr[(size_t)m * 1024 + j4];
    float4 b = *(const float4*)&aor[(size_t)m * 1024 + j4];
    v = make_float4(a.x + b.x, a.y + b.y, a.z + b.z, a.w + b.w);
  } else {
    float4 a = *(const float4*)&si[(size_t)m * 1024 + j4 - 1024];
    float4 b = *(const float4*)&aoi[(size_t)m * 1024 + j4 - 1024];
    v = make_float4(a.x + b.x, a.y + b.y, a.z + b.z, a.w + b.w);
  }
  ushort4 h, l;
  h.x = bf16rne(v.x); l.x = bf16rne(v.x - bf2f(h.x));
  h.y = bf16rne(v.y); l.y = bf16rne(v.y - bf2f(h.y));
  h.z = bf16rne(v.z); l.z = bf16rne(v.z - bf2f(h.z));
  h.w = bf16rne(v.w); l.w = bf16rne(v.w - bf2f(h.w));
  *(ushort4*)&Ahl[(size_t)m * 4096 + j4] = h;
  *(ushort4*)&Ahl[(size_t)m * 4096 + 2048 + j4] = l;
}

// ---------------- split+transpose FF weight: Bt[n=2048][hi2048|lo2048] ----------------
__global__ void split_b_kernel(const float* __restrict__ fr, const float* __restrict__ fi,
                               unsigned short* __restrict__ Bt) {
  __shared__ float tile[32][33];
  const int k0 = blockIdx.x * 32, n0 = blockIdx.y * 32;
  const int tid = threadIdx.x;
  #pragma unroll
  for (int p = 0; p < 4; ++p) {
    int e = p * 256 + tid;
    int kk = e >> 5, nn = e & 31;
    int k = k0 + kk, n = n0 + nn;
    float v;
    if (n < 1024) v = (k < 1024) ? fr[(size_t)k * 1024 + n] : -fi[(size_t)(k - 1024) * 1024 + n];
    else          v = (k < 1024) ? fi[(size_t)k * 1024 + (n - 1024)]
                                 : fr[(size_t)(k - 1024) * 1024 + (n - 1024)];
    tile[kk][nn] = v;
  }
  __syncthreads();
  #pragma unroll
  for (int p = 0; p < 4; ++p) {
    int e = p * 256 + tid;
    int nn = e >> 5, kk = e & 31;
    float v = tile[kk][nn];
    unsigned short h = bf16rne(v);
    unsigned short l = bf16rne(v - bf2f(h));
    Bt[(size_t)(n0 + nn) * 4096 + (k0 + kk)] = h;
    Bt[(size_t)(n0 + nn) * 4096 + 2048 + (k0 + kk)] = l;
  }
}

// ---------------- split readout weight: Wt[v=256][hi2048|lo2048] ----------------
__global__ void split_w_kernel(const float* __restrict__ wr, const float* __restrict__ wi,
                               unsigned short* __restrict__ Wt) {
  int idx = blockIdx.x * 256 + threadIdx.x;        // 256*512
  int v = idx >> 9;
  int k4 = (idx & 511) * 4;
  float4 a = (k4 < 1024) ? *(const float4*)&wr[(size_t)v * 1024 + k4]
                         : *(const float4*)&wi[(size_t)v * 1024 + k4 - 1024];
  ushort4 h, l;
  h.x = bf16rne(a.x); l.x = bf16rne(a.x - bf2f(h.x));
  h.y = bf16rne(a.y); l.y = bf16rne(a.y - bf2f(h.y));
  h.z = bf16rne(a.z); l.z = bf16rne(a.z - bf2f(h.z));
  h.w = bf16rne(a.w); l.w = bf16rne(a.w - bf2f(h.w));
  *(ushort4*)&Wt[(size_t)v * 4096 + k4] = h;
  *(ushort4*)&Wt[(size_t)v * 4096 + 2048 + k4] = l;
}

// ---------------- split-bf16 MFMA GEMM, 128x128 tile, BK=64, logical K=6144 ----------
template<bool RO>
__global__ __launch_bounds__(256, 2) void gemm_split(
    const unsigned short* __restrict__ A,   // [4096][4096]
    const unsigned short* __restrict__ Bt,  // [N][4096]
    float* __restrict__ o0, float* __restrict__ o1,
    const float* __restrict__ br, const float* __restrict__ bi) {
  __shared__ short As[128 * 64];
  __shared__ short Bs[128 * 64];
  const int tid = threadIdx.x;
  const int lane = tid & 63, wid = tid >> 6;
  const int m0 = blockIdx.x * 128, n0 = blockIdx.y * 128;
  const int wr = wid >> 1, wc = wid & 1;
  const int cl = lane & 15, rg = lane >> 4;

  f4x acc[4][4] = {};
  const int cbase = wid * 256;

  for (int kt = 0; kt < 96; ++kt) {
    const int k0 = kt * 64;
    const int pa = k0 & 4095;
    const int pb = (k0 < 4096) ? (k0 & 2047) : (k0 - 2048);
    #pragma unroll
    for (int it = 0; it < 4; ++it) {
      int c = cbase + it * 64 + lane;
      gload16(A + (size_t)(m0 + (c >> 3)) * 4096 + pa + (c & 7) * 8,
              As + (cbase + it * 64) * 8);
      gload16(Bt + (size_t)(n0 + (c >> 3)) * 4096 + pb + (c & 7) * 8,
              Bs + (cbase + it * 64) * 8);
    }
    __syncthreads();
    #pragma unroll
    for (int ks = 0; ks < 2; ++ks) {
      s8bf a[4], b[4];
      #pragma unroll
      for (int ms = 0; ms < 4; ++ms)
        a[ms] = *(const s8bf*)&As[(wr * 64 + ms * 16 + cl) * 64 + ks * 32 + rg * 8];
      #pragma unroll
      for (int ns = 0; ns < 4; ++ns)
        b[ns] = *(const s8bf*)&Bs[(wc * 64 + ns * 16 + cl) * 64 + ks * 32 + rg * 8];
      #pragma unroll
      for (int ms = 0; ms < 4; ++ms)
        #pragma unroll
        for (int ns = 0; ns < 4; ++ns)
          acc[ms][ns] = __builtin_amdgcn_mfma_f32_16x16x32_bf16(a[ms], b[ns], acc[ms][ns], 0, 0, 0);
    }
    __syncthreads();
  }

  const int colbase = n0 + wc * 64;
  if (!RO) {
    float* dst = (colbase < 1024) ? o0 : o1;
    const int cb = colbase & 1023;
    #pragma unroll
    for (int ms = 0; ms < 4; ++ms)
      #pragma unroll
      for (int r2 = 0; r2 < 4; ++r2) {
        const int grow = m0 + wr * 64 + ms * 16 + rg * 4 + r2;
        #pragma unroll
        for (int ns = 0; ns < 4; ++ns)
          dst[(size_t)grow * 1024 + cb + ns * 16 + cl] = acc[ms][ns][r2];
      }
  } else {
    #pragma unroll
    for (int ms = 0; ms < 4; ++ms)
      #pragma unroll
      for (int r2 = 0; r2 < 4; ++r2) {
        const int grow = m0 + wr * 64 + ms * 16 + rg * 4 + r2;
        #pragma unroll
        for (int ns = 0; ns < 4; ++ns) {
          const int gcol = colbase + ns * 16 + cl;
          o0[(size_t)grow * 256 + gcol] = acc[ms][ns][r2] + br[gcol] + bi[gcol];
        }
      }
  }
}

// ---------------- complex_norm fused with Z split: Zhl[4096][hi2048|lo2048] ----------
__global__ __launch_bounds__(256) void norm_split_kernel(
    const float* __restrict__ t2r, const float* __restrict__ t2i,
    unsigned short* __restrict__ Z) {
  const int row = blockIdx.x, tid = threadIdx.x;
  const int base = row * E_ + tid * 4;
  float4 zr = *(const float4*)&t2r[base];
  float4 zi = *(const float4*)&t2i[base];
  float mg[4];
  mg[0] = sqrtf(zr.x * zr.x + zi.x * zi.x);
  mg[1] = sqrtf(zr.y * zr.y + zi.y * zi.y);
  mg[2] = sqrtf(zr.z * zr.z + zi.z * zi.z);
  mg[3] = sqrtf(zr.w * zr.w + zi.w * zi.w);
  float s1 = mg[0] + mg[1] + mg[2] + mg[3];
  float s2 = mg[0]*mg[0] + mg[1]*mg[1] + mg[2]*mg[2] + mg[3]*mg[3];
  #pragma unroll
  for (int off = 1; off < 64; off <<= 1) {
    s1 += __shfl_xor(s1, off, 64);
    s2 += __shfl_xor(s2, off, 64);
  }
  __shared__ float ws1[4], ws2[4];
  if ((tid & 63) == 0) { ws1[tid >> 6] = s1; ws2[tid >> 6] = s2; }
  __syncthreads();
  s1 = ws1[0] + ws1[1] + ws1[2] + ws1[3];
  s2 = ws2[0] + ws2[1] + ws2[2] + ws2[3];
  float mean = s1 * (1.0f / 1024.0f);
  float var = (s2 - 1024.0f * mean * mean) * (1.0f / 1023.0f);  // ddof=1
  var = fmaxf(var, 0.0f);
  float inv_sd = 1.0f / (sqrtf(var) + 1e-5f);
  float sc[4];
  #pragma unroll
  for (int t = 0; t < 4; ++t)
    sc[t] = tanhf((mg[t] - mean) * inv_sd) / (mg[t] + 1e-5f);
  float a0 = zr.x * sc[0], a1 = zr.y * sc[1], a2 = zr.z * sc[2], a3 = zr.w * sc[3];
  float b0 = zi.x * sc[0], b1 = zi.y * sc[1], b2 = zi.z * sc[2], b3 = zi.w * sc[3];
  ushort4 hr, lr, hi_, li_;
  hr.x = bf16rne(a0); lr.x = bf16rne(a0 - bf2f(hr.x));
  hr.y = bf16rne(a1); lr.y = bf16rne(a1 - bf2f(hr.y));
  hr.z = bf16rne(a2); lr.z = bf16rne(a2 - bf2f(hr.z));
  hr.w = bf16rne(a3); lr.w = bf16rne(a3 - bf2f(hr.w));
  hi_.x = bf16rne(b0); li_.x = bf16rne(b0 - bf2f(hi_.x));
  hi_.y = bf16rne(b1); li_.y = bf16rne(b1 - bf2f(hi_.y));
  hi_.z = bf16rne(b2); li_.z = bf16rne(b2 - bf2f(hi_.z));
  hi_.w = bf16rne(b3); li_.w = bf16rne(b3 - bf2f(hi_.w));
  const size_t zb = (size_t)row * 4096 + tid * 4;
  *(ushort4*)&Z[zb]        = hr;
  *(ushort4*)&Z[zb + 1024] = hi_;
  *(ushort4*)&Z[zb + 2048] = lr;
  *(ushort4*)&Z[zb + 3072] = li_;
}

extern "C" void kernel_launch(void* const* d_in, const int* in_sizes, int n_in,
                              void* d_out, int out_size, void* d_ws, size_t ws_size,
                              hipStream_t stream) {
  const int*   x    = (const int*)d_in[0];
  const float* te   = (const float*)d_in[1];
  const float* pp   = (const float*)d_in[2];
  const float* qr   = (const float*)d_in[3];
  const float* kr   = (const float*)d_in[4];
  const float* vr   = (const float*)d_in[5];
  const float* ffr  = (const float*)d_in[6];
  const float* ffi  = (const float*)d_in[7];
  const float* rorw = (const float*)d_in[8];
  const float* rorb = (const float*)d_in[9];
  const float* roiw = (const float*)d_in[10];
  const float* roib = (const float*)d_in[11];
  float* out = (float*)d_out;

  const size_t NBSE = (size_t)B_ * S_ * E_;        // 4194304
  float* sr  = (float*)d_ws;                       // 16MB (reused as t2r)
  float* si  = sr + NBSE;                          // 16MB (reused as t2i)
  float* aor = si + NBSE;                          // 16MB ┐ reused as Zhl
  float* aoi = aor + NBSE;                         // 16MB ┘
  char* rc = (char*)(aoi + NBSE);                  // region C, 52428800 B
  // during attn: Kd (33.55MB) + Vd (16.78MB)
  unsigned short* Kd = (unsigned short*)rc;
  unsigned short* Vd = Kd + (size_t)64 * 64 * 4096;
  // after attn: Ahl (32MB) + Bt (16MB) + Wt (2MB)
  unsigned short* Ahl = (unsigned short*)rc;
  unsigned short* Bt  = Ahl + (size_t)4096 * 4096;
  unsigned short* Wt  = Bt + (size_t)2048 * 4096;
  float* tabs = (float*)(rc + 52428800);           // 24KB
  unsigned short* Zhl = (unsigned short*)aor;
  float* t2r = sr;
  float* t2i = si;

  rot_kernel<<<12, 256, 0, stream>>>(qr, kr, vr, tabs);
  embed_kernel<<<(int)(NBSE / 256), 256, 0, stream>>>(x, te, pp, sr, si);
  qkv_prep_kernel<<<dim3(32, 64), 256, 0, stream>>>(sr, si, tabs, Kd, Vd);
  attn_mfma_kernel<<<dim3(8, 64), 256, 0, stream>>>(sr, si, Kd, Vd, tabs, aor, aoi);
  split_b_kernel<<<dim3(64, 64), 256, 0, stream>>>(ffr, ffi, Bt);
  split_w_kernel<<<512, 256, 0, stream>>>(rorw, roiw, Wt);
  split_a_kernel<<<8192, 256, 0, stream>>>(sr, si, aor, aoi, Ahl);
  gemm_split<false><<<dim3(32, 16), 256, 0, stream>>>(Ahl, Bt, t2r, t2i, nullptr, nullptr);
  norm_split_kernel<<<B_ * S_, 256, 0, stream>>>(t2r, t2i, Zhl);
  gemm_split<true><<<dim3(32, 2), 256, 0, stream>>>(Zhl, Wt, out, nullptr, rorb, roib);
}

// Round 6
// 336.381 us; speedup vs baseline: 21.2226x; 1.2888x over previous
//
#include <hip/hip_runtime.h>
#include <math.h>

// PhaseMultiHeadDecoder: B=4, S=1024, E=1024, H=16, hd=64, V=256
// embed+qkv fused; attn: bf16 MFMA flash writing split-A directly;
// FF GEMM: split-bf16 3-term, K-split x2 (4 blocks/CU); RO GEMM: K-split x8.
#define B_ 4
#define S_ 1024
#define E_ 1024
#define H_ 16
#define V_ 256

typedef short s8bf __attribute__((ext_vector_type(8)));
typedef short s4bf __attribute__((ext_vector_type(4)));
typedef float f4x __attribute__((ext_vector_type(4)));

__device__ __forceinline__ unsigned short bf16rne(float v) {
  unsigned u = __float_as_uint(v);
  return (unsigned short)((u + 0x7FFF + ((u >> 16) & 1)) >> 16);
}
__device__ __forceinline__ float bf2f(unsigned short h) {
  return __uint_as_float(((unsigned)h) << 16);
}
__device__ __forceinline__ void gload16(const void* g, void* l) {
  __builtin_amdgcn_global_load_lds((const __attribute__((address_space(1))) void*)g,
                                   (__attribute__((address_space(3))) void*)l, 16, 0, 0);
}

#if defined(__has_builtin)
#if __has_builtin(__builtin_amdgcn_mfma_f32_16x16x16bf16_1k)
#define MFMA16(a, b, c) __builtin_amdgcn_mfma_f32_16x16x16bf16_1k(a, b, c, 0, 0, 0)
#endif
#endif
#ifndef MFMA16
__device__ __forceinline__ f4x mfma16_asm(s4bf a, s4bf b, f4x c) {
  asm volatile("v_mfma_f32_16x16x16_bf16 %0, %1, %2, %0" : "+v"(c) : "v"(a), "v"(b));
  return c;
}
#define MFMA16(a, b, c) mfma16_asm(a, b, c)
#endif

// ---------------- rotation cos/sin tables: tabs[3][2][1024] ----------------
__global__ void rot_kernel(const float* __restrict__ qr, const float* __restrict__ kr,
                           const float* __restrict__ vr, float* __restrict__ tabs) {
  int i = blockIdx.x * blockDim.x + threadIdx.x;
  if (i >= 3 * 1024) return;
  int which = i >> 10;
  int j = i & 1023;
  const float* src = which == 0 ? qr : (which == 1 ? kr : vr);
  float s, c;
  sincosf(src[j], &s, &c);
  tabs[which * 2048 + j] = c;
  tabs[which * 2048 + 1024 + j] = s;
}

// ---------------- fused embed + K'/V' prep ----------------
// Computes state = tanh(te[x])*exp(i*pp) for this block's (b, 32 rows, head h)
// tile, writes sr/si, and emits delta-rotated split-K' + raw bf16 V' fragments.
__global__ __launch_bounds__(256) void embed_qkv_kernel(
    const int* __restrict__ x, const float* __restrict__ te,
    const float* __restrict__ pp, const float* __restrict__ tabs,
    float* __restrict__ sr, float* __restrict__ si,
    unsigned short* __restrict__ Kd, unsigned short* __restrict__ Vd) {
  __shared__ unsigned short Kl2[8192];
  __shared__ unsigned short Vl2[4096];
  const int kt2 = blockIdx.x;          // 32-row group, 0..31
  const int bh = blockIdx.y;           // 0..63
  const int b = bh >> 4, h = bh & 15;
  const int tid = threadIdx.x;
  const float* qc = tabs + h * 64;
  const float* qs = tabs + 1024 + h * 64;
  const float* kc = tabs + 2048 + h * 64;
  const float* ks = tabs + 3072 + h * 64;
  #pragma unroll
  for (int p = 0; p < 8; ++p) {
    int id = p * 256 + tid;            // 2048 items = 32 rows x 64 dims
    int sl = id >> 6;
    int dd = id & 63;
    int s = kt2 * 32 + sl;
    int e = h * 64 + dd;
    int tok = x[b * 1024 + s];
    float mm = tanhf(te[tok * 1024 + e]);
    float sn, cs;
    sincosf(pp[s * 1024 + e], &sn, &cs);
    float re = mm * cs, im = mm * sn;
    size_t g = ((size_t)(b * 1024 + s)) * 1024 + e;
    sr[g] = re;
    si[g] = im;
    float cq = qc[dd], sq = qs[dd], ck = kc[dd], sk = ks[dd];
    float cd = cq * ck + sq * sk;      // cos(thq - thk)
    float sd = sq * ck - cq * sk;      // sin(thq - thk)
    float kr = re * cd + im * sd;
    float ki = im * cd - re * sd;
    unsigned short hr = bf16rne(kr), lr = bf16rne(kr - bf2f(hr));
    unsigned short hi2 = bf16rne(ki), li2 = bf16rne(ki - bf2f(hi2));
    int t = sl >> 4, key = sl & 15;
    int c0 = dd, c1 = 64 + dd, c2 = 128 + dd, c3 = 192 + dd;
    #define KOFF(c) (t * 4096 + ((((c) >> 5) * 4 + (((c) >> 3) & 3)) * 16 + key) * 8 + ((c) & 7))
    Kl2[KOFF(c0)] = hr;  Kl2[KOFF(c1)] = hi2;
    Kl2[KOFF(c2)] = lr;  Kl2[KOFF(c3)] = li2;
    #undef KOFF
    int kgk = key >> 2, jk = key & 3;
    #define VOFF(d) (t * 2048 + ((((d) >> 4) * 4 + kgk) * 16 + ((d) & 15)) * 4 + jk)
    Vl2[VOFF(dd)] = bf16rne(re);
    Vl2[VOFF(64 + dd)] = bf16rne(im);
    #undef VOFF
  }
  __syncthreads();
  unsigned short* kdst = Kd + ((size_t)(bh * 64 + kt2 * 2)) * 4096;
  unsigned short* vdst = Vd + ((size_t)(bh * 64 + kt2 * 2)) * 2048;
  #pragma unroll
  for (int p = 0; p < 4; ++p) {
    int c = p * 256 + tid;
    ((int4*)kdst)[c] = ((const int4*)Kl2)[c];
  }
  #pragma unroll
  for (int p = 0; p < 2; ++p) {
    int c = p * 256 + tid;
    ((int4*)vdst)[c] = ((const int4*)Vl2)[c];
  }
}

// ---------------- MFMA flash attention; epilogue writes split-A directly ------
__global__ __launch_bounds__(256, 2) void attn_mfma_kernel(
    const float* __restrict__ sr, const float* __restrict__ si,
    const unsigned short* __restrict__ Kd, const unsigned short* __restrict__ Vd,
    const float* __restrict__ tabs,
    unsigned short* __restrict__ Ahl) {
  __shared__ __align__(16) unsigned short Klds[4096];
  __shared__ __align__(16) unsigned short Vlds[2048];
  const int qt = blockIdx.x;           // 0..7
  const int bh = blockIdx.y;           // 0..63
  const int b = bh >> 4, h = bh & 15;
  const int tid = threadIdx.x, lane = tid & 63, wid = tid >> 6;
  const int cl = lane & 15, kg = lane >> 4;
  const int q0 = qt * 128, qw0 = q0 + wid * 32;

  s8bf qh[2][4], ql[2][4];
  #pragma unroll
  for (int qn = 0; qn < 2; ++qn) {
    int q = qw0 + qn * 16 + cl;
    const float* srow = sr + ((size_t)(b * 1024 + q)) * 1024 + h * 64;
    const float* irow = si + ((size_t)(b * 1024 + q)) * 1024 + h * 64;
    #pragma unroll
    for (int fa = 0; fa < 4; ++fa) {
      int f0 = fa * 32 + kg * 8;
      const float* src = (f0 < 64) ? (srow + f0) : (irow + (f0 - 64));
      float4 v0 = *(const float4*)src;
      float4 v1 = *(const float4*)(src + 4);
      float vv[8] = {v0.x, v0.y, v0.z, v0.w, v1.x, v1.y, v1.z, v1.w};
      #pragma unroll
      for (int j = 0; j < 8; ++j) {
        unsigned short hh = bf16rne(vv[j]);
        unsigned short lo = bf16rne(vv[j] - bf2f(hh));
        qh[qn][fa][j] = (short)hh;
        ql[qn][fa][j] = (short)lo;
      }
    }
  }

  f4x acc[2][8] = {};
  float m_[2] = {-1e30f, -1e30f}, l_[2] = {0.f, 0.f};
  const int ktmax = qt * 8 + 8;
  const int wqmax = qw0 + 31;

  for (int kt = 0; kt < ktmax; ++kt) {
    __syncthreads();
    const unsigned short* kbase = Kd + ((size_t)(bh * 64 + kt)) * 4096;
    const unsigned short* vbase = Vd + ((size_t)(bh * 64 + kt)) * 2048;
    #pragma unroll
    for (int it = 0; it < 2; ++it) {
      int c = wid * 128 + it * 64 + lane;
      gload16(kbase + (size_t)c * 8, Klds + (wid * 128 + it * 64) * 8);
    }
    gload16(vbase + (size_t)(wid * 64 + lane) * 8, Vlds + (wid * 64) * 8);
    __syncthreads();
    const int k0 = kt * 16;
    if (k0 <= wqmax) {
      f4x sc[2] = {};
      #pragma unroll
      for (int ks = 0; ks < 12; ++ks) {
        int f = (ks < 4) ? ks : ks - 4;
        s8bf ka = *(const s8bf*)&Klds[f * 512 + lane * 8];
        s8bf qb0 = (ks < 4) ? qh[0][ks] : (ks < 8 ? ql[0][ks - 4] : qh[0][ks - 8]);
        s8bf qb1 = (ks < 4) ? qh[1][ks] : (ks < 8 ? ql[1][ks - 4] : qh[1][ks - 8]);
        sc[0] = __builtin_amdgcn_mfma_f32_16x16x32_bf16(ka, qb0, sc[0], 0, 0, 0);
        sc[1] = __builtin_amdgcn_mfma_f32_16x16x32_bf16(ka, qb1, sc[1], 0, 0, 0);
      }
      #pragma unroll
      for (int qn = 0; qn < 2; ++qn) {
        int qcol = qw0 + qn * 16 + cl;
        if (k0 + 15 > qw0 + qn * 16) {
          #pragma unroll
          for (int r = 0; r < 4; ++r)
            if (k0 + kg * 4 + r > qcol) sc[qn][r] = -1e30f;
        }
        float mx = fmaxf(fmaxf(sc[qn][0], sc[qn][1]), fmaxf(sc[qn][2], sc[qn][3]));
        mx = fmaxf(mx, __shfl_xor(mx, 16, 64));
        mx = fmaxf(mx, __shfl_xor(mx, 32, 64));
        float mn = fmaxf(m_[qn], mx);
        float corr = __expf(m_[qn] - mn);
        float p0 = __expf(sc[qn][0] - mn), p1 = __expf(sc[qn][1] - mn);
        float p2 = __expf(sc[qn][2] - mn), p3 = __expf(sc[qn][3] - mn);
        float s0 = p0 + p1 + p2 + p3;
        s0 += __shfl_xor(s0, 16, 64);
        s0 += __shfl_xor(s0, 32, 64);
        l_[qn] = l_[qn] * corr + s0;
        bool resc = mn > m_[qn];
        m_[qn] = mn;
        if (__any(resc)) {
          #pragma unroll
          for (int mt = 0; mt < 8; ++mt) acc[qn][mt] *= corr;
        }
        s4bf pb;
        pb[0] = (short)bf16rne(p0); pb[1] = (short)bf16rne(p1);
        pb[2] = (short)bf16rne(p2); pb[3] = (short)bf16rne(p3);
        #pragma unroll
        for (int mt = 0; mt < 8; ++mt) {
          s4bf va = *(const s4bf*)&Vlds[mt * 256 + lane * 4];
          acc[qn][mt] = MFMA16(va, pb, acc[qn][mt]);
        }
      }
    }
  }
  // epilogue: /l, rotate by exp(i*thv), add state, split hi/lo -> Ahl
  #pragma unroll
  for (int qn = 0; qn < 2; ++qn) {
    float linv = 1.0f / l_[qn];
    int q = qw0 + qn * 16 + cl;
    size_t mrow = (size_t)(b * 1024 + q);
    size_t obase = mrow * 1024 + h * 64;
    size_t abase = mrow * 4096 + h * 64;
    #pragma unroll
    for (int mt = 0; mt < 4; ++mt) {
      int d0 = mt * 16 + kg * 4;
      float4 s_r = *(const float4*)&sr[obase + d0];
      float4 s_i = *(const float4*)&si[obase + d0];
      float srv[4] = {s_r.x, s_r.y, s_r.z, s_r.w};
      float siv[4] = {s_i.x, s_i.y, s_i.z, s_i.w};
      ushort4 uhr, ulr, uhi, uli;
      unsigned short* phr = (unsigned short*)&uhr;
      unsigned short* plr = (unsigned short*)&ulr;
      unsigned short* phi = (unsigned short*)&uhi;
      unsigned short* pli = (unsigned short*)&uli;
      #pragma unroll
      for (int r = 0; r < 4; ++r) {
        int d = d0 + r;
        float orv = acc[qn][mt][r] * linv;
        float oiv = acc[qn][mt + 4][r] * linv;
        float c = tabs[4096 + h * 64 + d], s = tabs[5120 + h * 64 + d];
        float ar = orv * c - oiv * s + srv[r];
        float ai = orv * s + oiv * c + siv[r];
        phr[r] = bf16rne(ar); plr[r] = bf16rne(ar - bf2f(phr[r]));
        phi[r] = bf16rne(ai); pli[r] = bf16rne(ai - bf2f(phi[r]));
      }
      *(ushort4*)&Ahl[abase + d0]        = uhr;   // hi real
      *(ushort4*)&Ahl[abase + 1024 + d0] = uhi;   // hi imag
      *(ushort4*)&Ahl[abase + 2048 + d0] = ulr;   // lo real
      *(ushort4*)&Ahl[abase + 3072 + d0] = uli;   // lo imag
    }
  }
}

// ---------------- split+transpose FF weight: Bt[n=2048][hi2048|lo2048] --------
__global__ void split_b_kernel(const float* __restrict__ fr, const float* __restrict__ fi,
                               unsigned short* __restrict__ Bt) {
  __shared__ float tile[32][33];
  const int k0 = blockIdx.x * 32, n0 = blockIdx.y * 32;
  const int tid = threadIdx.x;
  #pragma unroll
  for (int p = 0; p < 4; ++p) {
    int e = p * 256 + tid;
    int kk = e >> 5, nn = e & 31;
    int k = k0 + kk, n = n0 + nn;
    float v;
    if (n < 1024) v = (k < 1024) ? fr[(size_t)k * 1024 + n] : -fi[(size_t)(k - 1024) * 1024 + n];
    else          v = (k < 1024) ? fi[(size_t)k * 1024 + (n - 1024)]
                                 : fr[(size_t)(k - 1024) * 1024 + (n - 1024)];
    tile[kk][nn] = v;
  }
  __syncthreads();
  #pragma unroll
  for (int p = 0; p < 4; ++p) {
    int e = p * 256 + tid;
    int nn = e >> 5, kk = e & 31;
    float v = tile[kk][nn];
    unsigned short h = bf16rne(v);
    unsigned short l = bf16rne(v - bf2f(h));
    Bt[(size_t)(n0 + nn) * 4096 + (k0 + kk)] = h;
    Bt[(size_t)(n0 + nn) * 4096 + 2048 + (k0 + kk)] = l;
  }
}

// ---------------- split readout weight: Wt[v=256][hi2048|lo2048] ----------------
__global__ void split_w_kernel(const float* __restrict__ wr, const float* __restrict__ wi,
                               unsigned short* __restrict__ Wt) {
  int idx = blockIdx.x * 256 + threadIdx.x;
  int v = idx >> 9;
  int k4 = (idx & 511) * 4;
  float4 a = (k4 < 1024) ? *(const float4*)&wr[(size_t)v * 1024 + k4]
                         : *(const float4*)&wi[(size_t)v * 1024 + k4 - 1024];
  ushort4 h, l;
  h.x = bf16rne(a.x); l.x = bf16rne(a.x - bf2f(h.x));
  h.y = bf16rne(a.y); l.y = bf16rne(a.y - bf2f(h.y));
  h.z = bf16rne(a.z); l.z = bf16rne(a.z - bf2f(h.z));
  h.w = bf16rne(a.w); l.w = bf16rne(a.w - bf2f(h.w));
  *(ushort4*)&Wt[(size_t)v * 4096 + k4] = h;
  *(ushort4*)&Wt[(size_t)v * 4096 + 2048 + k4] = l;
}

// ---------------- FF GEMM: 128x128 tile, BK=64, K-split x2 -> f32 partials ----
__global__ __launch_bounds__(256, 2) void gemm_ff(
    const unsigned short* __restrict__ A,   // [4096][4096]
    const unsigned short* __restrict__ Bt,  // [2048][4096]
    float* __restrict__ pr0, float* __restrict__ pi0,
    float* __restrict__ pr1, float* __restrict__ pi1) {
  __shared__ short As[128 * 64];
  __shared__ short Bs[128 * 64];
  const int tid = threadIdx.x;
  const int lane = tid & 63, wid = tid >> 6;
  const int m0 = blockIdx.x * 128, n0 = blockIdx.y * 128;
  const int z = blockIdx.z;
  const int wr = wid >> 1, wc = wid & 1;
  const int cl = lane & 15, rg = lane >> 4;

  f4x acc[4][4] = {};
  const int cbase = wid * 256;

  for (int kt = z * 48; kt < z * 48 + 48; ++kt) {
    const int k0 = kt * 64;
    const int pa = k0 & 4095;
    const int pb = (k0 < 4096) ? (k0 & 2047) : (k0 - 2048);
    #pragma unroll
    for (int it = 0; it < 4; ++it) {
      int c = cbase + it * 64 + lane;
      gload16(A + (size_t)(m0 + (c >> 3)) * 4096 + pa + (c & 7) * 8,
              As + (cbase + it * 64) * 8);
      gload16(Bt + (size_t)(n0 + (c >> 3)) * 4096 + pb + (c & 7) * 8,
              Bs + (cbase + it * 64) * 8);
    }
    __syncthreads();
    #pragma unroll
    for (int ks = 0; ks < 2; ++ks) {
      s8bf a[4], b[4];
      #pragma unroll
      for (int ms = 0; ms < 4; ++ms)
        a[ms] = *(const s8bf*)&As[(wr * 64 + ms * 16 + cl) * 64 + ks * 32 + rg * 8];
      #pragma unroll
      for (int ns = 0; ns < 4; ++ns)
        b[ns] = *(const s8bf*)&Bs[(wc * 64 + ns * 16 + cl) * 64 + ks * 32 + rg * 8];
      #pragma unroll
      for (int ms = 0; ms < 4; ++ms)
        #pragma unroll
        for (int ns = 0; ns < 4; ++ns)
          acc[ms][ns] = __builtin_amdgcn_mfma_f32_16x16x32_bf16(a[ms], b[ns], acc[ms][ns], 0, 0, 0);
    }
    __syncthreads();
  }

  const int colbase = n0 + wc * 64;
  float* o_r = z ? pr1 : pr0;
  float* o_i = z ? pi1 : pi0;
  float* dst = (colbase < 1024) ? o_r : o_i;
  const int cb = colbase & 1023;
  #pragma unroll
  for (int ms = 0; ms < 4; ++ms)
    #pragma unroll
    for (int r2 = 0; r2 < 4; ++r2) {
      const int grow = m0 + wr * 64 + ms * 16 + rg * 4 + r2;
      #pragma unroll
      for (int ns = 0; ns < 4; ++ns)
        dst[(size_t)grow * 1024 + cb + ns * 16 + cl] = acc[ms][ns][r2];
    }
}

// ---------------- RO GEMM: 128x128 tile, K-split x8 -> f32 partials ----------
__global__ __launch_bounds__(256, 2) void gemm_ro(
    const unsigned short* __restrict__ Z,   // [4096][4096]
    const unsigned short* __restrict__ Wt,  // [256][4096]
    float* __restrict__ part) {             // [8][4096][256]
  __shared__ short As[128 * 64];
  __shared__ short Bs[128 * 64];
  const int tid = threadIdx.x;
  const int lane = tid & 63, wid = tid >> 6;
  const int m0 = blockIdx.x * 128, n0 = blockIdx.y * 128;
  const int z = blockIdx.z;
  const int wr = wid >> 1, wc = wid & 1;
  const int cl = lane & 15, rg = lane >> 4;

  f4x acc[4][4] = {};
  const int cbase = wid * 256;

  for (int kt = z * 12; kt < z * 12 + 12; ++kt) {
    const int k0 = kt * 64;
    const int pa = k0 & 4095;
    const int pb = (k0 < 4096) ? (k0 & 2047) : (k0 - 2048);
    #pragma unroll
    for (int it = 0; it < 4; ++it) {
      int c = cbase + it * 64 + lane;
      gload16(Z + (size_t)(m0 + (c >> 3)) * 4096 + pa + (c & 7) * 8,
              As + (cbase + it * 64) * 8);
      gload16(Wt + (size_t)(n0 + (c >> 3)) * 4096 + pb + (c & 7) * 8,
              Bs + (cbase + it * 64) * 8);
    }
    __syncthreads();
    #pragma unroll
    for (int ks = 0; ks < 2; ++ks) {
      s8bf a[4], b[4];
      #pragma unroll
      for (int ms = 0; ms < 4; ++ms)
        a[ms] = *(const s8bf*)&As[(wr * 64 + ms * 16 + cl) * 64 + ks * 32 + rg * 8];
      #pragma unroll
      for (int ns = 0; ns < 4; ++ns)
        b[ns] = *(const s8bf*)&Bs[(wc * 64 + ns * 16 + cl) * 64 + ks * 32 + rg * 8];
      #pragma unroll
      for (int ms = 0; ms < 4; ++ms)
        #pragma unroll
        for (int ns = 0; ns < 4; ++ns)
          acc[ms][ns] = __builtin_amdgcn_mfma_f32_16x16x32_bf16(a[ms], b[ns], acc[ms][ns], 0, 0, 0);
    }
    __syncthreads();
  }

  float* dst = part + (size_t)z * 4096 * 256;
  const int colbase = n0 + wc * 64;
  #pragma unroll
  for (int ms = 0; ms < 4; ++ms)
    #pragma unroll
    for (int r2 = 0; r2 < 4; ++r2) {
      const int grow = m0 + wr * 64 + ms * 16 + rg * 4 + r2;
      #pragma unroll
      for (int ns = 0; ns < 4; ++ns)
        dst[(size_t)grow * 256 + colbase + ns * 16 + cl] = acc[ms][ns][r2];
    }
}

// ---------------- complex_norm over FF partial sums -> split Z ----------------
__global__ __launch_bounds__(256) void norm_split_kernel(
    const float* __restrict__ pr0, const float* __restrict__ pi0,
    const float* __restrict__ pr1, const float* __restrict__ pi1,
    unsigned short* __restrict__ Z) {
  const int row = blockIdx.x, tid = threadIdx.x;
  const int base = row * E_ + tid * 4;
  float4 r0 = *(const float4*)&pr0[base];
  float4 r1 = *(const float4*)&pr1[base];
  float4 i0 = *(const float4*)&pi0[base];
  float4 i1 = *(const float4*)&pi1[base];
  float4 zr = make_float4(r0.x + r1.x, r0.y + r1.y, r0.z + r1.z, r0.w + r1.w);
  float4 zi = make_float4(i0.x + i1.x, i0.y + i1.y, i0.z + i1.z, i0.w + i1.w);
  float mg[4];
  mg[0] = sqrtf(zr.x * zr.x + zi.x * zi.x);
  mg[1] = sqrtf(zr.y * zr.y + zi.y * zi.y);
  mg[2] = sqrtf(zr.z * zr.z + zi.z * zi.z);
  mg[3] = sqrtf(zr.w * zr.w + zi.w * zi.w);
  float s1 = mg[0] + mg[1] + mg[2] + mg[3];
  float s2 = mg[0]*mg[0] + mg[1]*mg[1] + mg[2]*mg[2] + mg[3]*mg[3];
  #pragma unroll
  for (int off = 1; off < 64; off <<= 1) {
    s1 += __shfl_xor(s1, off, 64);
    s2 += __shfl_xor(s2, off, 64);
  }
  __shared__ float ws1[4], ws2[4];
  if ((tid & 63) == 0) { ws1[tid >> 6] = s1; ws2[tid >> 6] = s2; }
  __syncthreads();
  s1 = ws1[0] + ws1[1] + ws1[2] + ws1[3];
  s2 = ws2[0] + ws2[1] + ws2[2] + ws2[3];
  float mean = s1 * (1.0f / 1024.0f);
  float var = (s2 - 1024.0f * mean * mean) * (1.0f / 1023.0f);  // ddof=1
  var = fmaxf(var, 0.0f);
  float inv_sd = 1.0f / (sqrtf(var) + 1e-5f);
  float sc[4];
  #pragma unroll
  for (int t = 0; t < 4; ++t)
    sc[t] = tanhf((mg[t] - mean) * inv_sd) / (mg[t] + 1e-5f);
  float a0 = zr.x * sc[0], a1 = zr.y * sc[1], a2 = zr.z * sc[2], a3 = zr.w * sc[3];
  float b0 = zi.x * sc[0], b1 = zi.y * sc[1], b2 = zi.z * sc[2], b3 = zi.w * sc[3];
  ushort4 hr, lr, hi_, li_;
  hr.x = bf16rne(a0); lr.x = bf16rne(a0 - bf2f(hr.x));
  hr.y = bf16rne(a1); lr.y = bf16rne(a1 - bf2f(hr.y));
  hr.z = bf16rne(a2); lr.z = bf16rne(a2 - bf2f(hr.z));
  hr.w = bf16rne(a3); lr.w = bf16rne(a3 - bf2f(hr.w));
  hi_.x = bf16rne(b0); li_.x = bf16rne(b0 - bf2f(hi_.x));
  hi_.y = bf16rne(b1); li_.y = bf16rne(b1 - bf2f(hi_.y));
  hi_.z = bf16rne(b2); li_.z = bf16rne(b2 - bf2f(hi_.z));
  hi_.w = bf16rne(b3); li_.w = bf16rne(b3 - bf2f(hi_.w));
  const size_t zb = (size_t)row * 4096 + tid * 4;
  *(ushort4*)&Z[zb]        = hr;
  *(ushort4*)&Z[zb + 1024] = hi_;
  *(ushort4*)&Z[zb + 2048] = lr;
  *(ushort4*)&Z[zb + 3072] = li_;
}

// ---------------- reduce RO partials + biases -> out ----------------
__global__ void reduce_bias_kernel(const float* __restrict__ part,
                                   const float* __restrict__ rb,
                                   const float* __restrict__ ib,
                                   float* __restrict__ out) {
  int i4 = (blockIdx.x * 256 + threadIdx.x) * 4;   // < 4096*256
  int col = i4 & 255;
  float4 s = *(const float4*)&part[i4];
  #pragma unroll
  for (int z = 1; z < 8; ++z) {
    float4 v = *(const float4*)&part[(size_t)z * 1048576 + i4];
    s.x += v.x; s.y += v.y; s.z += v.z; s.w += v.w;
  }
  s.x += rb[col + 0] + ib[col + 0];
  s.y += rb[col + 1] + ib[col + 1];
  s.z += rb[col + 2] + ib[col + 2];
  s.w += rb[col + 3] + ib[col + 3];
  *(float4*)&out[i4] = s;
}

extern "C" void kernel_launch(void* const* d_in, const int* in_sizes, int n_in,
                              void* d_out, int out_size, void* d_ws, size_t ws_size,
                              hipStream_t stream) {
  const int*   x    = (const int*)d_in[0];
  const float* te   = (const float*)d_in[1];
  const float* pp   = (const float*)d_in[2];
  const float* qr   = (const float*)d_in[3];
  const float* kr   = (const float*)d_in[4];
  const float* vr   = (const float*)d_in[5];
  const float* ffr  = (const float*)d_in[6];
  const float* ffi  = (const float*)d_in[7];
  const float* rorw = (const float*)d_in[8];
  const float* rorb = (const float*)d_in[9];
  const float* roiw = (const float*)d_in[10];
  const float* roib = (const float*)d_in[11];
  float* out = (float*)d_out;

  char* W = (char*)d_ws;
  const size_t MiB = 1 << 20;
  // [0,16)MiB sr -> FF partial pr0 | [16,32) si -> pi0
  // [32,64) Ahl -> Zhl
  // [64,96) Kd -> Bt[64,80) + pr1[80,96)
  // [96,112) Vd -> pi1 -> ro_part(with pr1 region: [80,112))
  // [112,114) Wt | [114,+24K) tabs
  float* sr  = (float*)W;
  float* si  = (float*)(W + 16 * MiB);
  unsigned short* Ahl = (unsigned short*)(W + 32 * MiB);
  unsigned short* Kd  = (unsigned short*)(W + 64 * MiB);
  unsigned short* Vd  = (unsigned short*)(W + 96 * MiB);
  unsigned short* Bt  = (unsigned short*)(W + 64 * MiB);
  unsigned short* Wt  = (unsigned short*)(W + 112 * MiB);
  float* tabs = (float*)(W + 114 * MiB);
  float* pr0 = sr;
  float* pi0 = si;
  float* pr1 = (float*)(W + 80 * MiB);
  float* pi1 = (float*)(W + 96 * MiB);
  unsigned short* Zhl = Ahl;
  float* ro_part = (float*)(W + 80 * MiB);   // 8 x 4 MiB

  rot_kernel<<<12, 256, 0, stream>>>(qr, kr, vr, tabs);
  embed_qkv_kernel<<<dim3(32, 64), 256, 0, stream>>>(x, te, pp, tabs, sr, si, Kd, Vd);
  attn_mfma_kernel<<<dim3(8, 64), 256, 0, stream>>>(sr, si, Kd, Vd, tabs, Ahl);
  split_b_kernel<<<dim3(64, 64), 256, 0, stream>>>(ffr, ffi, Bt);
  split_w_kernel<<<512, 256, 0, stream>>>(rorw, roiw, Wt);
  gemm_ff<<<dim3(32, 16, 2), 256, 0, stream>>>(Ahl, Bt, pr0, pi0, pr1, pi1);
  norm_split_kernel<<<B_ * S_, 256, 0, stream>>>(pr0, pi0, pr1, pi1, Zhl);
  gemm_ro<<<dim3(32, 2, 8), 256, 0, stream>>>(Zhl, Wt, ro_part);
  reduce_bias_kernel<<<1024, 256, 0, stream>>>(ro_part, rorb, roib, out);
}

// Round 8
// 200.955 us; speedup vs baseline: 35.5248x; 1.6739x over previous
//
#include <hip/hip_runtime.h>
#include <math.h>

// PhaseMultiHeadDecoder: B=4, S=1024, E=1024, H=16, hd=64, V=256
// Full fp16 pipeline: embed+qkv fused; attn = fp16 MFMA flash (raw-state Q/V,
// delta-rotated K', transposed scores, fp16 P); FF/RO = plain fp16 MFMA GEMM
// (K=2048), m97 structure, K-split x2 / x8 with f32 partials.
#define B_ 4
#define S_ 1024
#define E_ 1024
#define H_ 16
#define V_ 256

typedef _Float16 h8 __attribute__((ext_vector_type(8)));
typedef _Float16 h4 __attribute__((ext_vector_type(4)));
typedef float f4x __attribute__((ext_vector_type(4)));

__device__ __forceinline__ void gload16(const void* g, void* l) {
  __builtin_amdgcn_global_load_lds((const __attribute__((address_space(1))) void*)g,
                                   (__attribute__((address_space(3))) void*)l, 16, 0, 0);
}

#define MFMA32F16(a, b, c) __builtin_amdgcn_mfma_f32_16x16x32_f16(a, b, c, 0, 0, 0)

#if defined(__has_builtin)
#if __has_builtin(__builtin_amdgcn_mfma_f32_16x16x16f16)
#define MFMA16F16(a, b, c) __builtin_amdgcn_mfma_f32_16x16x16f16(a, b, c, 0, 0, 0)
#endif
#endif
#ifndef MFMA16F16
__device__ __forceinline__ f4x mfma16f16_asm(h4 a, h4 b, f4x c) {
  asm volatile("v_mfma_f32_16x16x16_f16 %0, %1, %2, %0" : "+v"(c) : "v"(a), "v"(b));
  return c;
}
#define MFMA16F16(a, b, c) mfma16f16_asm(a, b, c)
#endif

// ---------------- rotation cos/sin tables: tabs[3][2][1024] ----------------
__global__ void rot_kernel(const float* __restrict__ qr, const float* __restrict__ kr,
                           const float* __restrict__ vr, float* __restrict__ tabs) {
  int i = blockIdx.x * blockDim.x + threadIdx.x;
  if (i >= 3 * 1024) return;
  int which = i >> 10;
  int j = i & 1023;
  const float* src = which == 0 ? qr : (which == 1 ? kr : vr);
  float s, c;
  sincosf(src[j], &s, &c);
  tabs[which * 2048 + j] = c;
  tabs[which * 2048 + 1024 + j] = s;
}

// ---------------- fused embed + K'/V' prep (fp16) ----------------
// K' per 16-key tile (2048 halves): ((f*4+kg)*16+key)*8+j, feature c=f*32+kg*8+j,
// c = [k'r(0-63)|k'i(64-127)].  V' per tile (2048 halves): ((d>>4)*4+key>>2)*16+(d&15))*4+(key&3)
__global__ __launch_bounds__(256) void embed_qkv_kernel(
    const int* __restrict__ x, const float* __restrict__ te,
    const float* __restrict__ pp, const float* __restrict__ tabs,
    float* __restrict__ sr, float* __restrict__ si,
    unsigned short* __restrict__ Kd, unsigned short* __restrict__ Vd) {
  __shared__ unsigned short Kl2[4096];
  __shared__ unsigned short Vl2[4096];
  const int kt2 = blockIdx.x;          // 32-row group, 0..31
  const int bh = blockIdx.y;           // 0..63
  const int b = bh >> 4, h = bh & 15;
  const int tid = threadIdx.x;
  const float* qc = tabs + h * 64;
  const float* qs = tabs + 1024 + h * 64;
  const float* kc = tabs + 2048 + h * 64;
  const float* ks = tabs + 3072 + h * 64;
  #pragma unroll
  for (int p = 0; p < 8; ++p) {
    int id = p * 256 + tid;            // 2048 items = 32 rows x 64 dims
    int sl = id >> 6;
    int dd = id & 63;
    int s = kt2 * 32 + sl;
    int e = h * 64 + dd;
    int tok = x[b * 1024 + s];
    float mm = tanhf(te[tok * 1024 + e]);
    float sn, cs;
    sincosf(pp[s * 1024 + e], &sn, &cs);
    float re = mm * cs, im = mm * sn;
    size_t g = ((size_t)(b * 1024 + s)) * 1024 + e;
    sr[g] = re;
    si[g] = im;
    float cq = qc[dd], sq = qs[dd], ck = kc[dd], sk = ks[dd];
    float cd = cq * ck + sq * sk;      // cos(thq - thk)
    float sd = sq * ck - cq * sk;      // sin(thq - thk)
    float kr = re * cd + im * sd;      // k-state rotated by -delta
    float ki = im * cd - re * sd;
    int t = sl >> 4, key = sl & 15;
    int c0 = dd, c1 = 64 + dd;
    #define KOFF(c) (t * 2048 + ((((c) >> 5) * 4 + (((c) >> 3) & 3)) * 16 + key) * 8 + ((c) & 7))
    *(_Float16*)&Kl2[KOFF(c0)] = (_Float16)kr;
    *(_Float16*)&Kl2[KOFF(c1)] = (_Float16)ki;
    #undef KOFF
    int kgk = key >> 2, jk = key & 3;
    #define VOFF(d) (t * 2048 + ((((d) >> 4) * 4 + kgk) * 16 + ((d) & 15)) * 4 + jk)
    *(_Float16*)&Vl2[VOFF(dd)] = (_Float16)re;
    *(_Float16*)&Vl2[VOFF(64 + dd)] = (_Float16)im;
    #undef VOFF
  }
  __syncthreads();
  unsigned short* kdst = Kd + ((size_t)(bh * 64 + kt2 * 2)) * 2048;
  unsigned short* vdst = Vd + ((size_t)(bh * 64 + kt2 * 2)) * 2048;
  #pragma unroll
  for (int p = 0; p < 2; ++p) {
    int c = p * 256 + tid;
    ((int4*)kdst)[c] = ((const int4*)Kl2)[c];
    ((int4*)vdst)[c] = ((const int4*)Vl2)[c];
  }
}

// ---------------- fp16 MFMA flash attention; epilogue writes fp16 A ----------
__global__ __launch_bounds__(256, 2) void attn_mfma_kernel(
    const float* __restrict__ sr, const float* __restrict__ si,
    const unsigned short* __restrict__ Kd, const unsigned short* __restrict__ Vd,
    const float* __restrict__ tabs,
    unsigned short* __restrict__ Af) {
  __shared__ __align__(16) unsigned short Klds[2048];
  __shared__ __align__(16) unsigned short Vlds[2048];
  const int qt = blockIdx.x;           // 0..7
  const int bh = blockIdx.y;           // 0..63
  const int b = bh >> 4, h = bh & 15;
  const int tid = threadIdx.x, lane = tid & 63, wid = tid >> 6;
  const int cl = lane & 15, kg = lane >> 4;
  const int q0 = qt * 128, qw0 = q0 + wid * 32;

  // Q^T b-frags from raw state, single fp16
  h8 qf[2][4];
  #pragma unroll
  for (int qn = 0; qn < 2; ++qn) {
    int q = qw0 + qn * 16 + cl;
    const float* srow = sr + ((size_t)(b * 1024 + q)) * 1024 + h * 64;
    const float* irow = si + ((size_t)(b * 1024 + q)) * 1024 + h * 64;
    #pragma unroll
    for (int ksx = 0; ksx < 4; ++ksx) {
      int f0 = ksx * 32 + kg * 8;
      const float* src = (f0 < 64) ? (srow + f0) : (irow + (f0 - 64));
      float4 v0 = *(const float4*)src;
      float4 v1 = *(const float4*)(src + 4);
      qf[qn][ksx][0] = (_Float16)v0.x; qf[qn][ksx][1] = (_Float16)v0.y;
      qf[qn][ksx][2] = (_Float16)v0.z; qf[qn][ksx][3] = (_Float16)v0.w;
      qf[qn][ksx][4] = (_Float16)v1.x; qf[qn][ksx][5] = (_Float16)v1.y;
      qf[qn][ksx][6] = (_Float16)v1.z; qf[qn][ksx][7] = (_Float16)v1.w;
    }
  }

  f4x acc[2][8] = {};                  // out^T: [qn][mt], d = mt*16+kg*4+r
  float m_[2] = {-1e30f, -1e30f}, l_[2] = {0.f, 0.f};
  const int ktmax = qt * 8 + 8;
  const int wqmax = qw0 + 31;

  for (int kt = 0; kt < ktmax; ++kt) {
    __syncthreads();
    const unsigned short* kbase = Kd + ((size_t)(bh * 64 + kt)) * 2048;
    const unsigned short* vbase = Vd + ((size_t)(bh * 64 + kt)) * 2048;
    gload16(kbase + (size_t)(wid * 64 + lane) * 8, Klds + (wid * 64) * 8);
    gload16(vbase + (size_t)(wid * 64 + lane) * 8, Vlds + (wid * 64) * 8);
    __syncthreads();
    const int k0 = kt * 16;
    if (k0 <= wqmax) {
      // scores^T over 4 fp16 k-steps (K=128 = [k'r|k'i])
      f4x sc[2] = {};
      #pragma unroll
      for (int ksx = 0; ksx < 4; ++ksx) {
        h8 ka = *(const h8*)&Klds[ksx * 512 + lane * 8];
        sc[0] = MFMA32F16(ka, qf[0][ksx], sc[0]);
        sc[1] = MFMA32F16(ka, qf[1][ksx], sc[1]);
      }
      #pragma unroll
      for (int qn = 0; qn < 2; ++qn) {
        int qcol = qw0 + qn * 16 + cl;
        if (k0 + 15 > qw0 + qn * 16) {
          #pragma unroll
          for (int r = 0; r < 4; ++r)
            if (k0 + kg * 4 + r > qcol) sc[qn][r] = -1e30f;
        }
        // online softmax (keys on kg*4+r -> in-lane + xor16 + xor32)
        float mx = fmaxf(fmaxf(sc[qn][0], sc[qn][1]), fmaxf(sc[qn][2], sc[qn][3]));
        mx = fmaxf(mx, __shfl_xor(mx, 16, 64));
        mx = fmaxf(mx, __shfl_xor(mx, 32, 64));
        float mn = fmaxf(m_[qn], mx);
        float corr = __expf(m_[qn] - mn);
        float p0 = __expf(sc[qn][0] - mn), p1 = __expf(sc[qn][1] - mn);
        float p2 = __expf(sc[qn][2] - mn), p3 = __expf(sc[qn][3] - mn);
        float s0 = p0 + p1 + p2 + p3;
        s0 += __shfl_xor(s0, 16, 64);
        s0 += __shfl_xor(s0, 32, 64);
        l_[qn] = l_[qn] * corr + s0;
        bool resc = mn > m_[qn];
        m_[qn] = mn;
        if (__any(resc)) {
          #pragma unroll
          for (int mt = 0; mt < 8; ++mt) acc[qn][mt] *= corr;
        }
        h4 pb;
        pb[0] = (_Float16)p0; pb[1] = (_Float16)p1;
        pb[2] = (_Float16)p2; pb[3] = (_Float16)p3;
        #pragma unroll
        for (int mt = 0; mt < 8; ++mt) {
          h4 va = *(const h4*)&Vlds[mt * 256 + lane * 4];
          acc[qn][mt] = MFMA16F16(va, pb, acc[qn][mt]);
        }
      }
    }
  }
  // epilogue: /l, rotate by exp(i*thv), add state, fp16 -> Af[4096][ar1024|ai1024]
  #pragma unroll
  for (int qn = 0; qn < 2; ++qn) {
    float linv = 1.0f / l_[qn];
    int q = qw0 + qn * 16 + cl;
    size_t mrow = (size_t)(b * 1024 + q);
    size_t obase = mrow * 1024 + h * 64;
    size_t abase = mrow * 2048 + h * 64;
    #pragma unroll
    for (int mt = 0; mt < 4; ++mt) {
      int d0 = mt * 16 + kg * 4;
      float4 s_r = *(const float4*)&sr[obase + d0];
      float4 s_i = *(const float4*)&si[obase + d0];
      float srv[4] = {s_r.x, s_r.y, s_r.z, s_r.w};
      float siv[4] = {s_i.x, s_i.y, s_i.z, s_i.w};
      h4 hr, hi;
      #pragma unroll
      for (int r = 0; r < 4; ++r) {
        int d = d0 + r;
        float orv = acc[qn][mt][r] * linv;
        float oiv = acc[qn][mt + 4][r] * linv;
        float c = tabs[4096 + h * 64 + d], s = tabs[5120 + h * 64 + d];
        hr[r] = (_Float16)(orv * c - oiv * s + srv[r]);
        hi[r] = (_Float16)(orv * s + oiv * c + siv[r]);
      }
      *(h4*)&Af[abase + d0]        = hr;   // real
      *(h4*)&Af[abase + 1024 + d0] = hi;   // imag
    }
  }
}

// ---------------- transpose FF weight -> fp16: Bt[2048][2048] ----------------
// Bv[k][n] = [[fr; -fi] | [fi; fr]];  Bt[n][k] = fp16(Bv[k][n])
__global__ void split_b_kernel(const float* __restrict__ fr, const float* __restrict__ fi,
                               unsigned short* __restrict__ Bt) {
  __shared__ float tile[32][33];
  const int k0 = blockIdx.x * 32, n0 = blockIdx.y * 32;
  const int tid = threadIdx.x;
  #pragma unroll
  for (int p = 0; p < 4; ++p) {
    int e = p * 256 + tid;
    int kk = e >> 5, nn = e & 31;
    int k = k0 + kk, n = n0 + nn;
    float v;
    if (n < 1024) v = (k < 1024) ? fr[(size_t)k * 1024 + n] : -fi[(size_t)(k - 1024) * 1024 + n];
    else          v = (k < 1024) ? fi[(size_t)k * 1024 + (n - 1024)]
                                 : fr[(size_t)(k - 1024) * 1024 + (n - 1024)];
    tile[kk][nn] = v;
  }
  __syncthreads();
  #pragma unroll
  for (int p = 0; p < 4; ++p) {
    int e = p * 256 + tid;
    int nn = e >> 5, kk = e & 31;
    *(_Float16*)&Bt[(size_t)(n0 + nn) * 2048 + (k0 + kk)] = (_Float16)tile[kk][nn];
  }
}

// ---------------- readout weight fp16: Wt[256][wr1024|wi1024] ----------------
__global__ void split_w_kernel(const float* __restrict__ wr, const float* __restrict__ wi,
                               unsigned short* __restrict__ Wt) {
  int idx = blockIdx.x * 256 + threadIdx.x;        // 256*512
  int v = idx >> 9;
  int k4 = (idx & 511) * 4;
  float4 a = (k4 < 1024) ? *(const float4*)&wr[(size_t)v * 1024 + k4]
                         : *(const float4*)&wi[(size_t)v * 1024 + k4 - 1024];
  h4 h;
  h[0] = (_Float16)a.x; h[1] = (_Float16)a.y;
  h[2] = (_Float16)a.z; h[3] = (_Float16)a.w;
  *(h4*)&Wt[(size_t)v * 2048 + k4] = h;
}

// ---------------- FF GEMM: fp16, 128x128 tile, BK=64, K=2048, K-split x2 ------
__global__ __launch_bounds__(256, 2) void gemm_ff(
    const unsigned short* __restrict__ A,   // [4096][2048] fp16 bits
    const unsigned short* __restrict__ Bt,  // [2048][2048]
    float* __restrict__ pr0, float* __restrict__ pi0,
    float* __restrict__ pr1, float* __restrict__ pi1) {
  __shared__ short As[128 * 64];
  __shared__ short Bs[128 * 64];
  const int tid = threadIdx.x;
  const int lane = tid & 63, wid = tid >> 6;
  const int m0 = blockIdx.x * 128, n0 = blockIdx.y * 128;
  const int z = blockIdx.z;
  const int wr = wid >> 1, wc = wid & 1;
  const int cl = lane & 15, rg = lane >> 4;

  f4x acc[4][4] = {};
  const int cbase = wid * 256;

  for (int kt = z * 16; kt < z * 16 + 16; ++kt) {
    const int k0 = kt * 64;
    #pragma unroll
    for (int it = 0; it < 4; ++it) {
      int c = cbase + it * 64 + lane;
      gload16(A + (size_t)(m0 + (c >> 3)) * 2048 + k0 + (c & 7) * 8,
              As + (cbase + it * 64) * 8);
      gload16(Bt + (size_t)(n0 + (c >> 3)) * 2048 + k0 + (c & 7) * 8,
              Bs + (cbase + it * 64) * 8);
    }
    __syncthreads();
    #pragma unroll
    for (int ks = 0; ks < 2; ++ks) {
      h8 a[4], b[4];
      #pragma unroll
      for (int ms = 0; ms < 4; ++ms)
        a[ms] = *(const h8*)&As[(wr * 64 + ms * 16 + cl) * 64 + ks * 32 + rg * 8];
      #pragma unroll
      for (int ns = 0; ns < 4; ++ns)
        b[ns] = *(const h8*)&Bs[(wc * 64 + ns * 16 + cl) * 64 + ks * 32 + rg * 8];
      #pragma unroll
      for (int ms = 0; ms < 4; ++ms)
        #pragma unroll
        for (int ns = 0; ns < 4; ++ns)
          acc[ms][ns] = MFMA32F16(a[ms], b[ns], acc[ms][ns]);
    }
    __syncthreads();
  }

  const int colbase = n0 + wc * 64;
  float* o_r = z ? pr1 : pr0;
  float* o_i = z ? pi1 : pi0;
  float* dst = (colbase < 1024) ? o_r : o_i;
  const int cb = colbase & 1023;
  #pragma unroll
  for (int ms = 0; ms < 4; ++ms)
    #pragma unroll
    for (int r2 = 0; r2 < 4; ++r2) {
      const int grow = m0 + wr * 64 + ms * 16 + rg * 4 + r2;
      #pragma unroll
      for (int ns = 0; ns < 4; ++ns)
        dst[(size_t)grow * 1024 + cb + ns * 16 + cl] = acc[ms][ns][r2];
    }
}

// ---------------- RO GEMM: fp16, 128x128 tile, K=2048, K-split x8 ------------
__global__ __launch_bounds__(256, 2) void gemm_ro(
    const unsigned short* __restrict__ Z,   // [4096][2048] fp16 bits
    const unsigned short* __restrict__ Wt,  // [256][2048]
    float* __restrict__ part) {             // [8][4096][256]
  __shared__ short As[128 * 64];
  __shared__ short Bs[128 * 64];
  const int tid = threadIdx.x;
  const int lane = tid & 63, wid = tid >> 6;
  const int m0 = blockIdx.x * 128, n0 = blockIdx.y * 128;
  const int z = blockIdx.z;
  const int wr = wid >> 1, wc = wid & 1;
  const int cl = lane & 15, rg = lane >> 4;

  f4x acc[4][4] = {};
  const int cbase = wid * 256;

  for (int kt = z * 4; kt < z * 4 + 4; ++kt) {
    const int k0 = kt * 64;
    #pragma unroll
    for (int it = 0; it < 4; ++it) {
      int c = cbase + it * 64 + lane;
      gload16(Z + (size_t)(m0 + (c >> 3)) * 2048 + k0 + (c & 7) * 8,
              As + (cbase + it * 64) * 8);
      gload16(Wt + (size_t)(n0 + (c >> 3)) * 2048 + k0 + (c & 7) * 8,
              Bs + (cbase + it * 64) * 8);
    }
    __syncthreads();
    #pragma unroll
    for (int ks = 0; ks < 2; ++ks) {
      h8 a[4], b[4];
      #pragma unroll
      for (int ms = 0; ms < 4; ++ms)
        a[ms] = *(const h8*)&As[(wr * 64 + ms * 16 + cl) * 64 + ks * 32 + rg * 8];
      #pragma unroll
      for (int ns = 0; ns < 4; ++ns)
        b[ns] = *(const h8*)&Bs[(wc * 64 + ns * 16 + cl) * 64 + ks * 32 + rg * 8];
      #pragma unroll
      for (int ms = 0; ms < 4; ++ms)
        #pragma unroll
        for (int ns = 0; ns < 4; ++ns)
          acc[ms][ns] = MFMA32F16(a[ms], b[ns], acc[ms][ns]);
    }
    __syncthreads();
  }

  float* dst = part + (size_t)z * 4096 * 256;
  const int colbase = n0 + wc * 64;
  #pragma unroll
  for (int ms = 0; ms < 4; ++ms)
    #pragma unroll
    for (int r2 = 0; r2 < 4; ++r2) {
      const int grow = m0 + wr * 64 + ms * 16 + rg * 4 + r2;
      #pragma unroll
      for (int ns = 0; ns < 4; ++ns)
        dst[(size_t)grow * 256 + colbase + ns * 16 + cl] = acc[ms][ns][r2];
    }
}

// ---------------- complex_norm over FF partial sums -> fp16 Z ----------------
__global__ __launch_bounds__(256) void norm_split_kernel(
    const float* __restrict__ pr0, const float* __restrict__ pi0,
    const float* __restrict__ pr1, const float* __restrict__ pi1,
    unsigned short* __restrict__ Z) {
  const int row = blockIdx.x, tid = threadIdx.x;
  const int base = row * E_ + tid * 4;
  float4 r0 = *(const float4*)&pr0[base];
  float4 r1 = *(const float4*)&pr1[base];
  float4 i0 = *(const float4*)&pi0[base];
  float4 i1 = *(const float4*)&pi1[base];
  float4 zr = make_float4(r0.x + r1.x, r0.y + r1.y, r0.z + r1.z, r0.w + r1.w);
  float4 zi = make_float4(i0.x + i1.x, i0.y + i1.y, i0.z + i1.z, i0.w + i1.w);
  float mg[4];
  mg[0] = sqrtf(zr.x * zr.x + zi.x * zi.x);
  mg[1] = sqrtf(zr.y * zr.y + zi.y * zi.y);
  mg[2] = sqrtf(zr.z * zr.z + zi.z * zi.z);
  mg[3] = sqrtf(zr.w * zr.w + zi.w * zi.w);
  float s1 = mg[0] + mg[1] + mg[2] + mg[3];
  float s2 = mg[0]*mg[0] + mg[1]*mg[1] + mg[2]*mg[2] + mg[3]*mg[3];
  #pragma unroll
  for (int off = 1; off < 64; off <<= 1) {
    s1 += __shfl_xor(s1, off, 64);
    s2 += __shfl_xor(s2, off, 64);
  }
  __shared__ float ws1[4], ws2[4];
  if ((tid & 63) == 0) { ws1[tid >> 6] = s1; ws2[tid >> 6] = s2; }
  __syncthreads();
  s1 = ws1[0] + ws1[1] + ws1[2] + ws1[3];
  s2 = ws2[0] + ws2[1] + ws2[2] + ws2[3];
  float mean = s1 * (1.0f / 1024.0f);
  float var = (s2 - 1024.0f * mean * mean) * (1.0f / 1023.0f);  // ddof=1
  var = fmaxf(var, 0.0f);
  float inv_sd = 1.0f / (sqrtf(var) + 1e-5f);
  float sc[4];
  #pragma unroll
  for (int t = 0; t < 4; ++t)
    sc[t] = tanhf((mg[t] - mean) * inv_sd) / (mg[t] + 1e-5f);
  h4 hr, hi;
  hr[0] = (_Float16)(zr.x * sc[0]); hr[1] = (_Float16)(zr.y * sc[1]);
  hr[2] = (_Float16)(zr.z * sc[2]); hr[3] = (_Float16)(zr.w * sc[3]);
  hi[0] = (_Float16)(zi.x * sc[0]); hi[1] = (_Float16)(zi.y * sc[1]);
  hi[2] = (_Float16)(zi.z * sc[2]); hi[3] = (_Float16)(zi.w * sc[3]);
  const size_t zb = (size_t)row * 2048 + tid * 4;
  *(h4*)&Z[zb]        = hr;
  *(h4*)&Z[zb + 1024] = hi;
}

// ---------------- reduce RO partials + biases -> out ----------------
__global__ void reduce_bias_kernel(const float* __restrict__ part,
                                   const float* __restrict__ rb,
                                   const float* __restrict__ ib,
                                   float* __restrict__ out) {
  int i4 = (blockIdx.x * 256 + threadIdx.x) * 4;   // < 4096*256
  int col = i4 & 255;
  float4 s = *(const float4*)&part[i4];
  #pragma unroll
  for (int z = 1; z < 8; ++z) {
    float4 v = *(const float4*)&part[(size_t)z * 1048576 + i4];
    s.x += v.x; s.y += v.y; s.z += v.z; s.w += v.w;
  }
  s.x += rb[col + 0] + ib[col + 0];
  s.y += rb[col + 1] + ib[col + 1];
  s.z += rb[col + 2] + ib[col + 2];
  s.w += rb[col + 3] + ib[col + 3];
  *(float4*)&out[i4] = s;
}

extern "C" void kernel_launch(void* const* d_in, const int* in_sizes, int n_in,
                              void* d_out, int out_size, void* d_ws, size_t ws_size,
                              hipStream_t stream) {
  const int*   x    = (const int*)d_in[0];
  const float* te   = (const float*)d_in[1];
  const float* pp   = (const float*)d_in[2];
  const float* qr   = (const float*)d_in[3];
  const float* kr   = (const float*)d_in[4];
  const float* vr   = (const float*)d_in[5];
  const float* ffr  = (const float*)d_in[6];
  const float* ffi  = (const float*)d_in[7];
  const float* rorw = (const float*)d_in[8];
  const float* rorb = (const float*)d_in[9];
  const float* roiw = (const float*)d_in[10];
  const float* roib = (const float*)d_in[11];
  float* out = (float*)d_out;

  char* W = (char*)d_ws;
  const size_t MiB = 1 << 20;
  // [0,16) sr -> pr0 | [16,32) si -> pi0
  // [32,48) Af -> Zhl
  // [48,64) Kd -> Bt[48,56) + Wt[56,57)   (after attn)
  // [64,80) Vd -> pr1 ┐
  // [80,96) pi1       ┴-> ro_part [64,96)  (after norm)
  // [96,+24K) tabs
  float* sr  = (float*)W;
  float* si  = (float*)(W + 16 * MiB);
  unsigned short* Af = (unsigned short*)(W + 32 * MiB);
  unsigned short* Kd = (unsigned short*)(W + 48 * MiB);
  unsigned short* Vd = (unsigned short*)(W + 64 * MiB);
  unsigned short* Bt = (unsigned short*)(W + 48 * MiB);
  unsigned short* Wt = (unsigned short*)(W + 56 * MiB);
  float* tabs = (float*)(W + 96 * MiB);
  float* pr0 = sr;
  float* pi0 = si;
  float* pr1 = (float*)(W + 64 * MiB);
  float* pi1 = (float*)(W + 80 * MiB);
  unsigned short* Zhl = Af;
  float* ro_part = (float*)(W + 64 * MiB);   // 8 x 4 MiB

  rot_kernel<<<12, 256, 0, stream>>>(qr, kr, vr, tabs);
  embed_qkv_kernel<<<dim3(32, 64), 256, 0, stream>>>(x, te, pp, tabs, sr, si, Kd, Vd);
  attn_mfma_kernel<<<dim3(8, 64), 256, 0, stream>>>(sr, si, Kd, Vd, tabs, Af);
  split_b_kernel<<<dim3(64, 64), 256, 0, stream>>>(ffr, ffi, Bt);
  split_w_kernel<<<512, 256, 0, stream>>>(rorw, roiw, Wt);
  gemm_ff<<<dim3(32, 16, 2), 256, 0, stream>>>(Af, Bt, pr0, pi0, pr1, pi1);
  norm_split_kernel<<<B_ * S_, 256, 0, stream>>>(pr0, pi0, pr1, pi1, Zhl);
  gemm_ro<<<dim3(32, 2, 8), 256, 0, stream>>>(Zhl, Wt, ro_part);
  reduce_bias_kernel<<<1024, 256, 0, stream>>>(ro_part, rorb, roib, out);
}

// Round 9
// 167.824 us; speedup vs baseline: 42.5381x; 1.1974x over previous
//
#include <hip/hip_runtime.h>
#include <math.h>

// PhaseMultiHeadDecoder: B=4, S=1024, E=1024, H=16, hd=64, V=256
// Full fp16 pipeline. attn: TQ=64, 4 blocks/CU all-resident, 32-key staging,
// bh->XCD swizzle for K/V L2 locality. FF/RO fp16 GEMM (K=2048) K-split.
#define B_ 4
#define S_ 1024
#define E_ 1024
#define H_ 16
#define V_ 256

typedef _Float16 h8 __attribute__((ext_vector_type(8)));
typedef _Float16 h4 __attribute__((ext_vector_type(4)));
typedef float f4x __attribute__((ext_vector_type(4)));

__device__ __forceinline__ void gload16(const void* g, void* l) {
  __builtin_amdgcn_global_load_lds((const __attribute__((address_space(1))) void*)g,
                                   (__attribute__((address_space(3))) void*)l, 16, 0, 0);
}

#define MFMA32F16(a, b, c) __builtin_amdgcn_mfma_f32_16x16x32_f16(a, b, c, 0, 0, 0)

#if defined(__has_builtin)
#if __has_builtin(__builtin_amdgcn_mfma_f32_16x16x16f16)
#define MFMA16F16(a, b, c) __builtin_amdgcn_mfma_f32_16x16x16f16(a, b, c, 0, 0, 0)
#endif
#endif
#ifndef MFMA16F16
__device__ __forceinline__ f4x mfma16f16_asm(h4 a, h4 b, f4x c) {
  asm volatile("v_mfma_f32_16x16x16_f16 %0, %1, %2, %0" : "+v"(c) : "v"(a), "v"(b));
  return c;
}
#define MFMA16F16(a, b, c) mfma16f16_asm(a, b, c)
#endif

// ---------------- rotation cos/sin tables: tabs[3][2][1024] ----------------
__global__ void rot_kernel(const float* __restrict__ qr, const float* __restrict__ kr,
                           const float* __restrict__ vr, float* __restrict__ tabs) {
  int i = blockIdx.x * blockDim.x + threadIdx.x;
  if (i >= 3 * 1024) return;
  int which = i >> 10;
  int j = i & 1023;
  const float* src = which == 0 ? qr : (which == 1 ? kr : vr);
  float s, c;
  sincosf(src[j], &s, &c);
  tabs[which * 2048 + j] = c;
  tabs[which * 2048 + 1024 + j] = s;
}

// ---------------- fused embed + K'/V' prep (fp16) ----------------
__global__ __launch_bounds__(256) void embed_qkv_kernel(
    const int* __restrict__ x, const float* __restrict__ te,
    const float* __restrict__ pp, const float* __restrict__ tabs,
    float* __restrict__ sr, float* __restrict__ si,
    unsigned short* __restrict__ Kd, unsigned short* __restrict__ Vd) {
  __shared__ unsigned short Kl2[4096];
  __shared__ unsigned short Vl2[4096];
  const int kt2 = blockIdx.x;          // 32-row group, 0..31
  const int bh = blockIdx.y;           // 0..63
  const int b = bh >> 4, h = bh & 15;
  const int tid = threadIdx.x;
  const float* qc = tabs + h * 64;
  const float* qs = tabs + 1024 + h * 64;
  const float* kc = tabs + 2048 + h * 64;
  const float* ks = tabs + 3072 + h * 64;
  #pragma unroll
  for (int p = 0; p < 8; ++p) {
    int id = p * 256 + tid;            // 2048 items = 32 rows x 64 dims
    int sl = id >> 6;
    int dd = id & 63;
    int s = kt2 * 32 + sl;
    int e = h * 64 + dd;
    int tok = x[b * 1024 + s];
    float mm = tanhf(te[tok * 1024 + e]);
    float sn, cs;
    sincosf(pp[s * 1024 + e], &sn, &cs);
    float re = mm * cs, im = mm * sn;
    size_t g = ((size_t)(b * 1024 + s)) * 1024 + e;
    sr[g] = re;
    si[g] = im;
    float cq = qc[dd], sq = qs[dd], ck = kc[dd], sk = ks[dd];
    float cd = cq * ck + sq * sk;      // cos(thq - thk)
    float sd = sq * ck - cq * sk;      // sin(thq - thk)
    float kr = re * cd + im * sd;      // k-state rotated by -delta
    float ki = im * cd - re * sd;
    int t = sl >> 4, key = sl & 15;
    int c0 = dd, c1 = 64 + dd;
    #define KOFF(c) (t * 2048 + ((((c) >> 5) * 4 + (((c) >> 3) & 3)) * 16 + key) * 8 + ((c) & 7))
    *(_Float16*)&Kl2[KOFF(c0)] = (_Float16)kr;
    *(_Float16*)&Kl2[KOFF(c1)] = (_Float16)ki;
    #undef KOFF
    int kgk = key >> 2, jk = key & 3;
    #define VOFF(d) (t * 2048 + ((((d) >> 4) * 4 + kgk) * 16 + ((d) & 15)) * 4 + jk)
    *(_Float16*)&Vl2[VOFF(dd)] = (_Float16)re;
    *(_Float16*)&Vl2[VOFF(64 + dd)] = (_Float16)im;
    #undef VOFF
  }
  __syncthreads();
  unsigned short* kdst = Kd + ((size_t)(bh * 64 + kt2 * 2)) * 2048;
  unsigned short* vdst = Vd + ((size_t)(bh * 64 + kt2 * 2)) * 2048;
  #pragma unroll
  for (int p = 0; p < 2; ++p) {
    int c = p * 256 + tid;
    ((int4*)kdst)[c] = ((const int4*)Kl2)[c];
    ((int4*)vdst)[c] = ((const int4*)Vl2)[c];
  }
}

// ---------------- fp16 MFMA flash attention, TQ=64, 32-key staging ----------
// grid 1024: flat -> low=flat&7 (XCD=bh&7), qt=(flat>>3)>>3, bh=((flat>>3)&7)<<3|low
__global__ __launch_bounds__(256, 4) void attn_mfma_kernel(
    const float* __restrict__ sr, const float* __restrict__ si,
    const unsigned short* __restrict__ Kd, const unsigned short* __restrict__ Vd,
    const float* __restrict__ tabs,
    unsigned short* __restrict__ Af) {
  __shared__ __align__(16) unsigned short Klds[4096];
  __shared__ __align__(16) unsigned short Vlds[4096];
  const int flat = blockIdx.x;
  const int low = flat & 7, rest = flat >> 3;
  const int qt = rest >> 3;            // 0..15
  const int bh = ((rest & 7) << 3) | low;
  const int b = bh >> 4, h = bh & 15;
  const int tid = threadIdx.x, lane = tid & 63, wid = tid >> 6;
  const int cl = lane & 15, kg = lane >> 4;
  const int q0 = qt * 64, qw0 = q0 + wid * 16;

  // Q^T b-frag (fp16), this wave's 16 q-rows
  h8 qf[4];
  {
    int q = qw0 + cl;
    const float* srow = sr + ((size_t)(b * 1024 + q)) * 1024 + h * 64;
    const float* irow = si + ((size_t)(b * 1024 + q)) * 1024 + h * 64;
    #pragma unroll
    for (int ksx = 0; ksx < 4; ++ksx) {
      int f0 = ksx * 32 + kg * 8;
      const float* src = (f0 < 64) ? (srow + f0) : (irow + (f0 - 64));
      float4 v0 = *(const float4*)src;
      float4 v1 = *(const float4*)(src + 4);
      qf[ksx][0] = (_Float16)v0.x; qf[ksx][1] = (_Float16)v0.y;
      qf[ksx][2] = (_Float16)v0.z; qf[ksx][3] = (_Float16)v0.w;
      qf[ksx][4] = (_Float16)v1.x; qf[ksx][5] = (_Float16)v1.y;
      qf[ksx][6] = (_Float16)v1.z; qf[ksx][7] = (_Float16)v1.w;
    }
  }

  f4x acc[8] = {};                     // out^T: [mt], d = mt*16+kg*4+r (mt<4 re, >=4 im)
  float m_ = -1e30f, l_ = 0.f;
  const int ktmax = qt * 4 + 4;        // 16-key tiles, always even
  const int wqmax = qw0 + 15;

  for (int kp = 0; kp < ktmax; kp += 2) {
    __syncthreads();
    const unsigned short* kbase = Kd + ((size_t)(bh * 64 + kp)) * 2048;
    const unsigned short* vbase = Vd + ((size_t)(bh * 64 + kp)) * 2048;
    #pragma unroll
    for (int r = 0; r < 2; ++r) {
      int c = r * 256 + wid * 64 + lane;
      gload16(kbase + (size_t)c * 8, Klds + (r * 256 + wid * 64) * 8);
      gload16(vbase + (size_t)c * 8, Vlds + (r * 256 + wid * 64) * 8);
    }
    __syncthreads();
    #pragma unroll
    for (int t2 = 0; t2 < 2; ++t2) {
      const int k0 = (kp + t2) * 16;
      if (k0 > wqmax) continue;        // wave-uniform skip
      f4x sc = {};
      #pragma unroll
      for (int ksx = 0; ksx < 4; ++ksx) {
        h8 ka = *(const h8*)&Klds[t2 * 2048 + ksx * 512 + lane * 8];
        sc = MFMA32F16(ka, qf[ksx], sc);
      }
      const int qcol = qw0 + cl;
      if (k0 + 15 > qw0) {
        #pragma unroll
        for (int r = 0; r < 4; ++r)
          if (k0 + kg * 4 + r > qcol) sc[r] = -1e30f;
      }
      float mx = fmaxf(fmaxf(sc[0], sc[1]), fmaxf(sc[2], sc[3]));
      mx = fmaxf(mx, __shfl_xor(mx, 16, 64));
      mx = fmaxf(mx, __shfl_xor(mx, 32, 64));
      float mn = fmaxf(m_, mx);
      float corr = __expf(m_ - mn);
      float p0 = __expf(sc[0] - mn), p1 = __expf(sc[1] - mn);
      float p2 = __expf(sc[2] - mn), p3 = __expf(sc[3] - mn);
      float s0 = p0 + p1 + p2 + p3;
      s0 += __shfl_xor(s0, 16, 64);
      s0 += __shfl_xor(s0, 32, 64);
      l_ = l_ * corr + s0;
      bool resc = mn > m_;
      m_ = mn;
      if (__any(resc)) {
        #pragma unroll
        for (int mt = 0; mt < 8; ++mt) acc[mt] *= corr;
      }
      h4 pb;
      pb[0] = (_Float16)p0; pb[1] = (_Float16)p1;
      pb[2] = (_Float16)p2; pb[3] = (_Float16)p3;
      #pragma unroll
      for (int mt = 0; mt < 8; ++mt) {
        h4 va = *(const h4*)&Vlds[t2 * 2048 + mt * 256 + lane * 4];
        acc[mt] = MFMA16F16(va, pb, acc[mt]);
      }
    }
  }
  // epilogue: /l, rotate by exp(i*thv), add state, fp16 -> Af[4096][re1024|im1024]
  {
    float linv = 1.0f / l_;
    int q = qw0 + cl;
    size_t mrow = (size_t)(b * 1024 + q);
    size_t obase = mrow * 1024 + h * 64;
    size_t abase = mrow * 2048 + h * 64;
    #pragma unroll
    for (int mt = 0; mt < 4; ++mt) {
      int d0 = mt * 16 + kg * 4;
      float4 s_r = *(const float4*)&sr[obase + d0];
      float4 s_i = *(const float4*)&si[obase + d0];
      float srv[4] = {s_r.x, s_r.y, s_r.z, s_r.w};
      float siv[4] = {s_i.x, s_i.y, s_i.z, s_i.w};
      h4 hr, hi;
      #pragma unroll
      for (int r = 0; r < 4; ++r) {
        int d = d0 + r;
        float orv = acc[mt][r] * linv;
        float oiv = acc[mt + 4][r] * linv;
        float c = tabs[4096 + h * 64 + d], s = tabs[5120 + h * 64 + d];
        hr[r] = (_Float16)(orv * c - oiv * s + srv[r]);
        hi[r] = (_Float16)(orv * s + oiv * c + siv[r]);
      }
      *(h4*)&Af[abase + d0]        = hr;   // real
      *(h4*)&Af[abase + 1024 + d0] = hi;   // imag
    }
  }
}

// ---------------- transpose FF weight -> fp16: Bt[2048][2048] ----------------
__global__ void split_b_kernel(const float* __restrict__ fr, const float* __restrict__ fi,
                               unsigned short* __restrict__ Bt) {
  __shared__ float tile[32][33];
  const int k0 = blockIdx.x * 32, n0 = blockIdx.y * 32;
  const int tid = threadIdx.x;
  #pragma unroll
  for (int p = 0; p < 4; ++p) {
    int e = p * 256 + tid;
    int kk = e >> 5, nn = e & 31;
    int k = k0 + kk, n = n0 + nn;
    float v;
    if (n < 1024) v = (k < 1024) ? fr[(size_t)k * 1024 + n] : -fi[(size_t)(k - 1024) * 1024 + n];
    else          v = (k < 1024) ? fi[(size_t)k * 1024 + (n - 1024)]
                                 : fr[(size_t)(k - 1024) * 1024 + (n - 1024)];
    tile[kk][nn] = v;
  }
  __syncthreads();
  #pragma unroll
  for (int p = 0; p < 4; ++p) {
    int e = p * 256 + tid;
    int nn = e >> 5, kk = e & 31;
    *(_Float16*)&Bt[(size_t)(n0 + nn) * 2048 + (k0 + kk)] = (_Float16)tile[kk][nn];
  }
}

// ---------------- readout weight fp16: Wt[256][wr1024|wi1024] ----------------
__global__ void split_w_kernel(const float* __restrict__ wr, const float* __restrict__ wi,
                               unsigned short* __restrict__ Wt) {
  int idx = blockIdx.x * 256 + threadIdx.x;        // 256*512
  int v = idx >> 9;
  int k4 = (idx & 511) * 4;
  float4 a = (k4 < 1024) ? *(const float4*)&wr[(size_t)v * 1024 + k4]
                         : *(const float4*)&wi[(size_t)v * 1024 + k4 - 1024];
  h4 h;
  h[0] = (_Float16)a.x; h[1] = (_Float16)a.y;
  h[2] = (_Float16)a.z; h[3] = (_Float16)a.w;
  *(h4*)&Wt[(size_t)v * 2048 + k4] = h;
}

// ---------------- FF GEMM: fp16, 128x128 tile, BK=64, K=2048, K-split x2 ------
__global__ __launch_bounds__(256, 4) void gemm_ff(
    const unsigned short* __restrict__ A,   // [4096][2048] fp16 bits
    const unsigned short* __restrict__ Bt,  // [2048][2048]
    float* __restrict__ pr0, float* __restrict__ pi0,
    float* __restrict__ pr1, float* __restrict__ pi1) {
  __shared__ short As[128 * 64];
  __shared__ short Bs[128 * 64];
  const int tid = threadIdx.x;
  const int lane = tid & 63, wid = tid >> 6;
  const int m0 = blockIdx.x * 128, n0 = blockIdx.y * 128;
  const int z = blockIdx.z;
  const int wr = wid >> 1, wc = wid & 1;
  const int cl = lane & 15, rg = lane >> 4;

  f4x acc[4][4] = {};
  const int cbase = wid * 256;

  for (int kt = z * 16; kt < z * 16 + 16; ++kt) {
    const int k0 = kt * 64;
    #pragma unroll
    for (int it = 0; it < 4; ++it) {
      int c = cbase + it * 64 + lane;
      gload16(A + (size_t)(m0 + (c >> 3)) * 2048 + k0 + (c & 7) * 8,
              As + (cbase + it * 64) * 8);
      gload16(Bt + (size_t)(n0 + (c >> 3)) * 2048 + k0 + (c & 7) * 8,
              Bs + (cbase + it * 64) * 8);
    }
    __syncthreads();
    #pragma unroll
    for (int ks = 0; ks < 2; ++ks) {
      h8 a[4], b[4];
      #pragma unroll
      for (int ms = 0; ms < 4; ++ms)
        a[ms] = *(const h8*)&As[(wr * 64 + ms * 16 + cl) * 64 + ks * 32 + rg * 8];
      #pragma unroll
      for (int ns = 0; ns < 4; ++ns)
        b[ns] = *(const h8*)&Bs[(wc * 64 + ns * 16 + cl) * 64 + ks * 32 + rg * 8];
      #pragma unroll
      for (int ms = 0; ms < 4; ++ms)
        #pragma unroll
        for (int ns = 0; ns < 4; ++ns)
          acc[ms][ns] = MFMA32F16(a[ms], b[ns], acc[ms][ns]);
    }
    __syncthreads();
  }

  const int colbase = n0 + wc * 64;
  float* o_r = z ? pr1 : pr0;
  float* o_i = z ? pi1 : pi0;
  float* dst = (colbase < 1024) ? o_r : o_i;
  const int cb = colbase & 1023;
  #pragma unroll
  for (int ms = 0; ms < 4; ++ms)
    #pragma unroll
    for (int r2 = 0; r2 < 4; ++r2) {
      const int grow = m0 + wr * 64 + ms * 16 + rg * 4 + r2;
      #pragma unroll
      for (int ns = 0; ns < 4; ++ns)
        dst[(size_t)grow * 1024 + cb + ns * 16 + cl] = acc[ms][ns][r2];
    }
}

// ---------------- RO GEMM: fp16, 128x128 tile, K=2048, K-split x8 ------------
__global__ __launch_bounds__(256, 4) void gemm_ro(
    const unsigned short* __restrict__ Z,   // [4096][2048] fp16 bits
    const unsigned short* __restrict__ Wt,  // [256][2048]
    float* __restrict__ part) {             // [8][4096][256]
  __shared__ short As[128 * 64];
  __shared__ short Bs[128 * 64];
  const int tid = threadIdx.x;
  const int lane = tid & 63, wid = tid >> 6;
  const int m0 = blockIdx.x * 128, n0 = blockIdx.y * 128;
  const int z = blockIdx.z;
  const int wr = wid >> 1, wc = wid & 1;
  const int cl = lane & 15, rg = lane >> 4;

  f4x acc[4][4] = {};
  const int cbase = wid * 256;

  for (int kt = z * 4; kt < z * 4 + 4; ++kt) {
    const int k0 = kt * 64;
    #pragma unroll
    for (int it = 0; it < 4; ++it) {
      int c = cbase + it * 64 + lane;
      gload16(Z + (size_t)(m0 + (c >> 3)) * 2048 + k0 + (c & 7) * 8,
              As + (cbase + it * 64) * 8);
      gload16(Wt + (size_t)(n0 + (c >> 3)) * 2048 + k0 + (c & 7) * 8,
              Bs + (cbase + it * 64) * 8);
    }
    __syncthreads();
    #pragma unroll
    for (int ks = 0; ks < 2; ++ks) {
      h8 a[4], b[4];
      #pragma unroll
      for (int ms = 0; ms < 4; ++ms)
        a[ms] = *(const h8*)&As[(wr * 64 + ms * 16 + cl) * 64 + ks * 32 + rg * 8];
      #pragma unroll
      for (int ns = 0; ns < 4; ++ns)
        b[ns] = *(const h8*)&Bs[(wc * 64 + ns * 16 + cl) * 64 + ks * 32 + rg * 8];
      #pragma unroll
      for (int ms = 0; ms < 4; ++ms)
        #pragma unroll
        for (int ns = 0; ns < 4; ++ns)
          acc[ms][ns] = MFMA32F16(a[ms], b[ns], acc[ms][ns]);
    }
    __syncthreads();
  }

  float* dst = part + (size_t)z * 4096 * 256;
  const int colbase = n0 + wc * 64;
  #pragma unroll
  for (int ms = 0; ms < 4; ++ms)
    #pragma unroll
    for (int r2 = 0; r2 < 4; ++r2) {
      const int grow = m0 + wr * 64 + ms * 16 + rg * 4 + r2;
      #pragma unroll
      for (int ns = 0; ns < 4; ++ns)
        dst[(size_t)grow * 256 + colbase + ns * 16 + cl] = acc[ms][ns][r2];
    }
}

// ---------------- complex_norm over FF partial sums -> fp16 Z ----------------
__global__ __launch_bounds__(256) void norm_split_kernel(
    const float* __restrict__ pr0, const float* __restrict__ pi0,
    const float* __restrict__ pr1, const float* __restrict__ pi1,
    unsigned short* __restrict__ Z) {
  const int row = blockIdx.x, tid = threadIdx.x;
  const int base = row * E_ + tid * 4;
  float4 r0 = *(const float4*)&pr0[base];
  float4 r1 = *(const float4*)&pr1[base];
  float4 i0 = *(const float4*)&pi0[base];
  float4 i1 = *(const float4*)&pi1[base];
  float4 zr = make_float4(r0.x + r1.x, r0.y + r1.y, r0.z + r1.z, r0.w + r1.w);
  float4 zi = make_float4(i0.x + i1.x, i0.y + i1.y, i0.z + i1.z, i0.w + i1.w);
  float mg[4];
  mg[0] = sqrtf(zr.x * zr.x + zi.x * zi.x);
  mg[1] = sqrtf(zr.y * zr.y + zi.y * zi.y);
  mg[2] = sqrtf(zr.z * zr.z + zi.z * zi.z);
  mg[3] = sqrtf(zr.w * zr.w + zi.w * zi.w);
  float s1 = mg[0] + mg[1] + mg[2] + mg[3];
  float s2 = mg[0]*mg[0] + mg[1]*mg[1] + mg[2]*mg[2] + mg[3]*mg[3];
  #pragma unroll
  for (int off = 1; off < 64; off <<= 1) {
    s1 += __shfl_xor(s1, off, 64);
    s2 += __shfl_xor(s2, off, 64);
  }
  __shared__ float ws1[4], ws2[4];
  if ((tid & 63) == 0) { ws1[tid >> 6] = s1; ws2[tid >> 6] = s2; }
  __syncthreads();
  s1 = ws1[0] + ws1[1] + ws1[2] + ws1[3];
  s2 = ws2[0] + ws2[1] + ws2[2] + ws2[3];
  float mean = s1 * (1.0f / 1024.0f);
  float var = (s2 - 1024.0f * mean * mean) * (1.0f / 1023.0f);  // ddof=1
  var = fmaxf(var, 0.0f);
  float inv_sd = 1.0f / (sqrtf(var) + 1e-5f);
  float sc[4];
  #pragma unroll
  for (int t = 0; t < 4; ++t)
    sc[t] = tanhf((mg[t] - mean) * inv_sd) / (mg[t] + 1e-5f);
  h4 hr, hi;
  hr[0] = (_Float16)(zr.x * sc[0]); hr[1] = (_Float16)(zr.y * sc[1]);
  hr[2] = (_Float16)(zr.z * sc[2]); hr[3] = (_Float16)(zr.w * sc[3]);
  hi[0] = (_Float16)(zi.x * sc[0]); hi[1] = (_Float16)(zi.y * sc[1]);
  hi[2] = (_Float16)(zi.z * sc[2]); hi[3] = (_Float16)(zi.w * sc[3]);
  const size_t zb = (size_t)row * 2048 + tid * 4;
  *(h4*)&Z[zb]        = hr;
  *(h4*)&Z[zb + 1024] = hi;
}

// ---------------- reduce RO partials + biases -> out ----------------
__global__ void reduce_bias_kernel(const float* __restrict__ part,
                                   const float* __restrict__ rb,
                                   const float* __restrict__ ib,
                                   float* __restrict__ out) {
  int i4 = (blockIdx.x * 256 + threadIdx.x) * 4;   // < 4096*256
  int col = i4 & 255;
  float4 s = *(const float4*)&part[i4];
  #pragma unroll
  for (int z = 1; z < 8; ++z) {
    float4 v = *(const float4*)&part[(size_t)z * 1048576 + i4];
    s.x += v.x; s.y += v.y; s.z += v.z; s.w += v.w;
  }
  s.x += rb[col + 0] + ib[col + 0];
  s.y += rb[col + 1] + ib[col + 1];
  s.z += rb[col + 2] + ib[col + 2];
  s.w += rb[col + 3] + ib[col + 3];
  *(float4*)&out[i4] = s;
}

extern "C" void kernel_launch(void* const* d_in, const int* in_sizes, int n_in,
                              void* d_out, int out_size, void* d_ws, size_t ws_size,
                              hipStream_t stream) {
  const int*   x    = (const int*)d_in[0];
  const float* te   = (const float*)d_in[1];
  const float* pp   = (const float*)d_in[2];
  const float* qr   = (const float*)d_in[3];
  const float* kr   = (const float*)d_in[4];
  const float* vr   = (const float*)d_in[5];
  const float* ffr  = (const float*)d_in[6];
  const float* ffi  = (const float*)d_in[7];
  const float* rorw = (const float*)d_in[8];
  const float* rorb = (const float*)d_in[9];
  const float* roiw = (const float*)d_in[10];
  const float* roib = (const float*)d_in[11];
  float* out = (float*)d_out;

  char* W = (char*)d_ws;
  const size_t MiB = 1 << 20;
  // [0,16) sr -> pr0 | [16,32) si -> pi0
  // [32,48) Af -> Zhl
  // [48,64) Kd -> Bt[48,56) + Wt[56,57)   (after attn)
  // [64,80) Vd -> pr1 ┐
  // [80,96) pi1       ┴-> ro_part [64,96)  (after norm)
  // [96,+24K) tabs
  float* sr  = (float*)W;
  float* si  = (float*)(W + 16 * MiB);
  unsigned short* Af = (unsigned short*)(W + 32 * MiB);
  unsigned short* Kd = (unsigned short*)(W + 48 * MiB);
  unsigned short* Vd = (unsigned short*)(W + 64 * MiB);
  unsigned short* Bt = (unsigned short*)(W + 48 * MiB);
  unsigned short* Wt = (unsigned short*)(W + 56 * MiB);
  float* tabs = (float*)(W + 96 * MiB);
  float* pr0 = sr;
  float* pi0 = si;
  float* pr1 = (float*)(W + 64 * MiB);
  float* pi1 = (float*)(W + 80 * MiB);
  unsigned short* Zhl = Af;
  float* ro_part = (float*)(W + 64 * MiB);   // 8 x 4 MiB

  rot_kernel<<<12, 256, 0, stream>>>(qr, kr, vr, tabs);
  embed_qkv_kernel<<<dim3(32, 64), 256, 0, stream>>>(x, te, pp, tabs, sr, si, Kd, Vd);
  attn_mfma_kernel<<<1024, 256, 0, stream>>>(sr, si, Kd, Vd, tabs, Af);
  split_b_kernel<<<dim3(64, 64), 256, 0, stream>>>(ffr, ffi, Bt);
  split_w_kernel<<<512, 256, 0, stream>>>(rorw, roiw, Wt);
  gemm_ff<<<dim3(32, 16, 2), 256, 0, stream>>>(Af, Bt, pr0, pi0, pr1, pi1);
  norm_split_kernel<<<B_ * S_, 256, 0, stream>>>(pr0, pi0, pr1, pi1, Zhl);
  gemm_ro<<<dim3(32, 2, 8), 256, 0, stream>>>(Zhl, Wt, ro_part);
  reduce_bias_kernel<<<1024, 256, 0, stream>>>(ro_part, rorb, roib, out);
}